// Round 2
// baseline (4619.972 us; speedup 1.0000x reference)
//
#include <hip/hip_runtime.h>

typedef unsigned short u16;

#define NN 16384   // nodes
#define EE 131072  // edges
#define ERO 32768  // readout edges
#define DF 1024    // appearance dim
#define DL 300     // word2vec dim
#define DS 16      // spatial dim
#define NC 117     // classes

__device__ __forceinline__ float bf2f(u16 x) {
  unsigned int u = ((unsigned int)x) << 16;
  float f;
  __builtin_memcpy(&f, &u, 4);
  return f;
}
__device__ __forceinline__ u16 f2bf(float f) {
  unsigned int u;
  __builtin_memcpy(&u, &f, 4);
  u = (u + 0x7FFFu + ((u >> 16) & 1u)) >> 16;
  return (u16)u;
}

// dtype-adaptive scalar load: f==1 -> f32, f==0 -> bf16
__device__ __forceinline__ float ld1(const void* p, size_t i, int f) {
  return f ? ((const float*)p)[i] : bf2f(((const u16*)p)[i]);
}
// 4-wide contiguous load (alignment: callers guarantee i%4==0 on 16B-aligned base)
__device__ __forceinline__ void ld4(const void* p, size_t i, int f,
                                    float& x, float& y, float& z, float& w) {
  if (f) {
    float4 v = *(const float4*)((const float*)p + i);
    x = v.x; y = v.y; z = v.z; w = v.w;
  } else {
    ushort4 v = *(const ushort4*)((const u16*)p + i);
    x = bf2f(v.x); y = bf2f(v.y); z = bf2f(v.z); w = bf2f(v.w);
  }
}
// element-offset that respects dtype (host can't know dtype, so offsets are in elements)
__device__ __forceinline__ const void* eoff(const void* p, size_t off, int f) {
  return f ? (const void*)((const float*)p + off) : (const void*)((const u16*)p + off);
}

// Decide input dtype from feat's first 64 32-bit words. bf16 storage: lower u16
// is a real bf16 value of N(0,1) -> exponent ~127, all in [97,157]. f32 storage:
// lower u16 is random mantissa bits -> exponent uniform, ~24% in range.
__global__ void detect_kernel(const unsigned int* __restrict__ w, int* __restrict__ flag) {
  unsigned int x = w[threadIdx.x];
  int e = (x >> 7) & 0xFF;            // bf16 exponent of the lower u16
  int ok = (e >= 97 && e <= 157);
  unsigned long long m = __ballot(ok);
  if (threadIdx.x == 0) flag[0] = (__popcll(m) >= 48) ? 0 : 1;  // 0=bf16, 1=f32
}

// C[M,Nc] = act(A1@B1 + A2@B2 + bias). Row-major, f32 accum.
// inA/inB/inBias: 1 = operand is a harness input (dtype per flag), 0 = bf16 workspace.
// 64x64 tile, BK=16, 256 threads, 4x4 microtile. M must be multiple of 64.
__global__ __launch_bounds__(256) void gemm2(
    const int* __restrict__ flag,
    const void* __restrict__ A1, int lda1,
    const void* __restrict__ B1b, size_t offB1, int ldb1, int K1, int inA1, int inB1,
    const void* __restrict__ A2, int lda2,
    const void* __restrict__ B2b, size_t offB2, int ldb2, int K2, int inA2, int inB2,
    const void* __restrict__ bias, int inBias,
    void* __restrict__ Cv, int ldc, int Nc, int relu, int c_f32)
{
  const int fin = flag[0];
  __shared__ float As[16][68];
  __shared__ float Bs[16][68];
  const int tid = threadIdx.x;
  const int row0 = blockIdx.y << 6;
  const int col0 = blockIdx.x << 6;
  const int tr = tid >> 4;
  const int tc = tid & 15;
  const int ar = tid >> 2;          // 0..63 A-load row
  const int ak = (tid & 3) << 2;    // 0,4,8,12 A-load k (x4)
  const int bk = tid >> 4;          // 0..15 B-load k
  const int bc = (tid & 15) << 2;   // B-load col (x4)
  float acc[4][4] = {};

  for (int pair = 0; pair < 2; ++pair) {
    const void* A = pair ? A2 : A1;
    if (!A) break;
    const int af = (pair ? inA2 : inA1) ? fin : 0;
    const int bf = (pair ? inB2 : inB1) ? fin : 0;
    const void* B = eoff(pair ? B2b : B1b, pair ? offB2 : offB1, bf);
    const int lda = pair ? lda2 : lda1;
    const int ldb = pair ? ldb2 : ldb1;
    const int K   = pair ? K2 : K1;
    for (int k0 = 0; k0 < K; k0 += 16) {
      float a0 = 0.f, a1 = 0.f, a2 = 0.f, a3 = 0.f;
      if (k0 + ak < K)  // K%4==0 so whole 4-vec in range when first elem is
        ld4(A, (size_t)(row0 + ar) * lda + k0 + ak, af, a0, a1, a2, a3);
      As[ak + 0][ar] = a0; As[ak + 1][ar] = a1;
      As[ak + 2][ar] = a2; As[ak + 3][ar] = a3;

      float b0 = 0.f, b1 = 0.f, b2 = 0.f, b3 = 0.f;
      if (k0 + bk < K) {
        const size_t bo = (size_t)(k0 + bk) * ldb + col0 + bc;
        const int rem = Nc - (col0 + bc);
        if (rem >= 1) b0 = ld1(B, bo + 0, bf);
        if (rem >= 2) b1 = ld1(B, bo + 1, bf);
        if (rem >= 3) b2 = ld1(B, bo + 2, bf);
        if (rem >= 4) b3 = ld1(B, bo + 3, bf);
      }
      Bs[bk][bc + 0] = b0; Bs[bk][bc + 1] = b1;
      Bs[bk][bc + 2] = b2; Bs[bk][bc + 3] = b3;
      __syncthreads();

      #pragma unroll
      for (int kk = 0; kk < 16; ++kk) {
        const float4 a = *(const float4*)&As[kk][tr << 2];
        const float4 b = *(const float4*)&Bs[kk][tc << 2];
        acc[0][0] = fmaf(a.x, b.x, acc[0][0]);
        acc[0][1] = fmaf(a.x, b.y, acc[0][1]);
        acc[0][2] = fmaf(a.x, b.z, acc[0][2]);
        acc[0][3] = fmaf(a.x, b.w, acc[0][3]);
        acc[1][0] = fmaf(a.y, b.x, acc[1][0]);
        acc[1][1] = fmaf(a.y, b.y, acc[1][1]);
        acc[1][2] = fmaf(a.y, b.z, acc[1][2]);
        acc[1][3] = fmaf(a.y, b.w, acc[1][3]);
        acc[2][0] = fmaf(a.z, b.x, acc[2][0]);
        acc[2][1] = fmaf(a.z, b.y, acc[2][1]);
        acc[2][2] = fmaf(a.z, b.z, acc[2][2]);
        acc[2][3] = fmaf(a.z, b.w, acc[2][3]);
        acc[3][0] = fmaf(a.w, b.x, acc[3][0]);
        acc[3][1] = fmaf(a.w, b.y, acc[3][1]);
        acc[3][2] = fmaf(a.w, b.z, acc[3][2]);
        acc[3][3] = fmaf(a.w, b.w, acc[3][3]);
      }
      __syncthreads();
    }
  }

  #pragma unroll
  for (int i = 0; i < 4; ++i) {
    const int r = row0 + (tr << 2) + i;
    #pragma unroll
    for (int j = 0; j < 4; ++j) {
      const int c = col0 + (tc << 2) + j;
      if (c < Nc) {
        float v = acc[i][j];
        if (bias) v += ld1(bias, c, inBias ? fin : 0);
        if (relu) v = fmaxf(v, 0.f);
        if (c_f32) ((float*)Cv)[(size_t)r * ldc + c] = v;
        else       ((u16*)Cv)[(size_t)r * ldc + c] = f2bf(v);
      }
    }
  }
}

// degree count (int atomics, exact)
__global__ void cnt_kernel(const int* __restrict__ edst, int* __restrict__ cnt) {
  const int i = blockIdx.x * 256 + threadIdx.x;
  if (i < EE) atomicAdd(&cnt[edst[i]], 1);
}

// Fused edge pass: m = relu(P1[src]+P2[dst]+s_f@W_es+b_e) -> atomic agg
//                 ml = relu(Q1[src]+Q2[dst]+b_el)          -> atomic aggl
// 8 edges per block; W_es (16x1024) staged to LDS once.
__global__ __launch_bounds__(256) void edge_pass(
    const int* __restrict__ flag,
    const u16* __restrict__ P1, const u16* __restrict__ P2,
    const u16* __restrict__ Q1, const u16* __restrict__ Q2,
    const void* __restrict__ s_f,
    const void* __restrict__ W_eb, size_t offWes,
    const void* __restrict__ b_e, const void* __restrict__ b_el,
    const int* __restrict__ esrc, const int* __restrict__ edst,
    float* __restrict__ agg, float* __restrict__ aggl)
{
  const int fin = flag[0];
  __shared__ float wes[16 * DF];  // 64 KB
  const void* W_es = eoff(W_eb, offWes, fin);
  const int tid = threadIdx.x;
  for (int i = tid; i < 16 * DF; i += 256) wes[i] = ld1(W_es, i, fin);
  __syncthreads();

  const int c4 = tid << 2;  // this thread's 4 appearance columns
  const float be0 = ld1(b_e, c4 + 0, fin), be1 = ld1(b_e, c4 + 1, fin);
  const float be2 = ld1(b_e, c4 + 2, fin), be3 = ld1(b_e, c4 + 3, fin);

  const int e0 = blockIdx.x << 3;
  for (int ee = 0; ee < 8; ++ee) {
    const int e = e0 + ee;
    const int s = esrc[e];
    const int d = edst[e];
    float sf[16];
    #pragma unroll
    for (int k = 0; k < 16; ++k) sf[k] = ld1(s_f, (size_t)e * DS + k, fin);

    const ushort4 p1 = *(const ushort4*)(P1 + (size_t)s * DF + c4);
    const ushort4 p2 = *(const ushort4*)(P2 + (size_t)d * DF + c4);
    float v0 = bf2f(p1.x) + bf2f(p2.x) + be0;
    float v1 = bf2f(p1.y) + bf2f(p2.y) + be1;
    float v2 = bf2f(p1.z) + bf2f(p2.z) + be2;
    float v3 = bf2f(p1.w) + bf2f(p2.w) + be3;
    #pragma unroll
    for (int k = 0; k < 16; ++k) {
      const float4 w = *(const float4*)&wes[k * DF + c4];
      v0 = fmaf(sf[k], w.x, v0);
      v1 = fmaf(sf[k], w.y, v1);
      v2 = fmaf(sf[k], w.z, v2);
      v3 = fmaf(sf[k], w.w, v3);
    }
    v0 = fmaxf(v0, 0.f); v1 = fmaxf(v1, 0.f);
    v2 = fmaxf(v2, 0.f); v3 = fmaxf(v3, 0.f);
    float* ap = agg + (size_t)d * DF + c4;
    unsafeAtomicAdd(ap + 0, v0);
    unsafeAtomicAdd(ap + 1, v1);
    unsafeAtomicAdd(ap + 2, v2);
    unsafeAtomicAdd(ap + 3, v3);

    for (int c = tid; c < DL; c += 256) {
      float ml = bf2f(Q1[(size_t)s * DL + c]) + bf2f(Q2[(size_t)d * DL + c]) + ld1(b_el, c, fin);
      ml = fmaxf(ml, 0.f);
      unsafeAtomicAdd(aggl + (size_t)d * DL + c, ml);
    }
  }
}

// mean-normalize f32 accumulator -> bf16
__global__ void norm_kernel(const float* __restrict__ acc, const int* __restrict__ cnt,
                            u16* __restrict__ out, int Dc, int total) {
  const int i = blockIdx.x * 256 + threadIdx.x;
  if (i >= total) return;
  const int n = i / Dc;
  const float c = fmaxf((float)cnt[n], 1.0f);
  out[i] = f2bf(acc[i] / c);
}

// pred[e] = Rd[dst] + Rs[src] + s_f_ro[e]@Wp_s + b_p ; 8 edges per block
__global__ __launch_bounds__(128) void readout_kernel(
    const int* __restrict__ flag,
    const float* __restrict__ Rd, const float* __restrict__ Rs,
    const void* __restrict__ s_f_ro,
    const void* __restrict__ W_pb, size_t offWps,
    const void* __restrict__ b_p,
    const int* __restrict__ rsrc, const int* __restrict__ rdst, void* __restrict__ out)
{
  const int fin = flag[0];
  __shared__ float wps[16 * NC];
  const void* Wp_s = eoff(W_pb, offWps, fin);
  const int tid = threadIdx.x;
  for (int i = tid; i < 16 * NC; i += 128) wps[i] = ld1(Wp_s, i, fin);
  __syncthreads();
  const float bp = (tid < NC) ? ld1(b_p, tid, fin) : 0.f;

  const int e0 = blockIdx.x << 3;
  for (int ee = 0; ee < 8; ++ee) {
    const int e = e0 + ee;
    const int s = rsrc[e];
    const int d = rdst[e];
    if (tid < NC) {
      float acc = Rd[(size_t)d * NC + tid] + Rs[(size_t)s * NC + tid] + bp;
      #pragma unroll
      for (int k = 0; k < 16; ++k)
        acc = fmaf(ld1(s_f_ro, (size_t)e * DS + k, fin), wps[k * NC + tid], acc);
      if (fin) ((float*)out)[(size_t)e * NC + tid] = acc;
      else     ((u16*)out)[(size_t)e * NC + tid] = f2bf(acc);
    }
  }
}

extern "C" void kernel_launch(void* const* d_in, const int* in_sizes, int n_in,
                              void* d_out, int out_size, void* d_ws, size_t ws_size,
                              hipStream_t stream)
{
  const void* feat  = d_in[0];
  const void* w2v   = d_in[1];
  const void* s_f   = d_in[2];
  const void* s_fro = d_in[3];
  const void* W_e   = d_in[4];
  const void* b_e   = d_in[5];
  const void* W_el  = d_in[6];
  const void* b_el  = d_in[7];
  const void* W_nu  = d_in[8];
  const void* b_nu  = d_in[9];
  const void* W_nul = d_in[10];
  const void* b_nul = d_in[11];
  const void* W_p   = d_in[12];
  const void* b_p   = d_in[13];
  const int* esrc  = (const int*)d_in[14];
  const int* edst  = (const int*)d_in[15];
  const int* rsrc  = (const int*)d_in[16];
  const int* rdst  = (const int*)d_in[17];

  // workspace layout (with aliasing); peak ~174 MB
  char* ws = (char*)d_ws;
  int*   flag = (int*)ws;                          // dtype flag (16B slot)
  float* agg  = (float*)(ws + 256);                // NN*DF f32   (zeroed)
  float* aggl = agg + (size_t)NN * DF;             // NN*DL f32   (zeroed)
  int*   cnt  = (int*)(aggl + (size_t)NN * DL);    // NN int      (zeroed)
  u16*   P1   = (u16*)(cnt + NN);                  // NN*DF bf16
  u16*   P2   = P1 + (size_t)NN * DF;              // NN*DF bf16
  u16*   Q1   = P2 + (size_t)NN * DF;              // NN*DL bf16
  u16*   Q2   = Q1 + (size_t)NN * DL;              // NN*DL bf16
  // aliases, valid by stream ordering:
  u16*   aggn  = P1;   // P1 dead after edge_pass
  u16*   aggln = Q1;   // Q1 dead after edge_pass
  u16*   newf  = P2;   // P2 dead after edge_pass
  u16*   newl  = Q2;   // Q2 dead after edge_pass
  float* Rd    = agg;  // agg dead after norm
  float* Rs    = agg + (size_t)NN * NC;

  detect_kernel<<<1, 64, 0, stream>>>((const unsigned int*)feat, flag);
  hipMemsetAsync(agg, 0, ((size_t)NN * DF + (size_t)NN * DL + NN) * 4, stream);
  cnt_kernel<<<EE / 256, 256, 0, stream>>>(edst, cnt);

  dim3 gF(DF / 64, NN / 64);            // (16,256)
  dim3 gL((DL + 63) / 64, NN / 64);     // (5,256)
  dim3 gC((NC + 63) / 64, NN / 64);     // (2,256)

  // node-level projections for the edge MLPs
  gemm2<<<gF, 256, 0, stream>>>(flag, feat, DF, W_e, 0,                 DF, DF, 1, 1,
                                nullptr, 0, nullptr, 0, 0, 0, 0, 0,
                                nullptr, 0, P1, DF, DF, 0, 0);
  gemm2<<<gF, 256, 0, stream>>>(flag, feat, DF, W_e, (size_t)DF * DF,   DF, DF, 1, 1,
                                nullptr, 0, nullptr, 0, 0, 0, 0, 0,
                                nullptr, 0, P2, DF, DF, 0, 0);
  gemm2<<<gL, 256, 0, stream>>>(flag, w2v, DL, W_el, 0,                 DL, DL, 1, 1,
                                nullptr, 0, nullptr, 0, 0, 0, 0, 0,
                                nullptr, 0, Q1, DL, DL, 0, 0);
  gemm2<<<gL, 256, 0, stream>>>(flag, w2v, DL, W_el, (size_t)DL * DL,   DL, DL, 1, 1,
                                nullptr, 0, nullptr, 0, 0, 0, 0, 0,
                                nullptr, 0, Q2, DL, DL, 0, 0);

  edge_pass<<<EE / 8, 256, 0, stream>>>(flag, P1, P2, Q1, Q2, s_f,
                                        W_e, (size_t)2 * DF * DF, b_e, b_el,
                                        esrc, edst, agg, aggl);

  norm_kernel<<<(NN * DF) / 256, 256, 0, stream>>>(agg, cnt, aggn, DF, NN * DF);
  norm_kernel<<<(NN * DL) / 256, 256, 0, stream>>>(aggl, cnt, aggln, DL, NN * DL);

  // node updates
  gemm2<<<gF, 256, 0, stream>>>(flag, feat, DF, W_nu, 0,                DF, DF, 1, 1,
                                aggn, DF, W_nu, (size_t)DF * DF,        DF, DF, 0, 1,
                                b_nu, 1, newf, DF, DF, 1, 0);
  gemm2<<<gL, 256, 0, stream>>>(flag, w2v, DL, W_nul, 0,                DL, DL, 1, 1,
                                aggln, DL, W_nul, (size_t)DL * DL,      DL, DL, 0, 1,
                                b_nul, 1, newl, DL, DL, 1, 0);

  // node-level readout projections (f32 out)
  gemm2<<<gC, 256, 0, stream>>>(flag, newf, DF, W_p, 0,                 NC, DF, 0, 1,
                                newl, DL, W_p, (size_t)DF * NC,         NC, DL, 0, 1,
                                nullptr, 0, Rd, NC, NC, 0, 1);
  gemm2<<<gC, 256, 0, stream>>>(flag, newl, DL, W_p, (size_t)(DF + DL + DS) * NC,      NC, DL, 0, 1,
                                newf, DF, W_p, (size_t)(DF + DL + DS + DL) * NC,       NC, DF, 0, 1,
                                nullptr, 0, Rs, NC, NC, 0, 1);

  readout_kernel<<<ERO / 8, 128, 0, stream>>>(flag, Rd, Rs, s_fro,
                                              W_p, (size_t)(DF + DL) * NC, b_p,
                                              rsrc, rdst, d_out);
}

// Round 3
// 2830.903 us; speedup vs baseline: 1.6320x; 1.6320x over previous
//
#include <hip/hip_runtime.h>

typedef unsigned short u16;

#define NN 16384   // nodes
#define EE 131072  // edges
#define ERO 32768  // readout edges
#define DF 1024    // appearance dim
#define DL 300     // word2vec dim
#define DS 16      // spatial dim
#define NC 117     // classes

__device__ __forceinline__ float bf2f(u16 x) {
  unsigned int u = ((unsigned int)x) << 16;
  float f;
  __builtin_memcpy(&f, &u, 4);
  return f;
}
__device__ __forceinline__ u16 f2bf(float f) {
  unsigned int u;
  __builtin_memcpy(&u, &f, 4);
  u = (u + 0x7FFFu + ((u >> 16) & 1u)) >> 16;
  return (u16)u;
}

// dtype-adaptive scalar load: f==1 -> f32, f==0 -> bf16
__device__ __forceinline__ float ld1(const void* p, size_t i, int f) {
  return f ? ((const float*)p)[i] : bf2f(((const u16*)p)[i]);
}
__device__ __forceinline__ void ld4(const void* p, size_t i, int f,
                                    float& x, float& y, float& z, float& w) {
  if (f) {
    float4 v = *(const float4*)((const float*)p + i);
    x = v.x; y = v.y; z = v.z; w = v.w;
  } else {
    ushort4 v = *(const ushort4*)((const u16*)p + i);
    x = bf2f(v.x); y = bf2f(v.y); z = bf2f(v.z); w = bf2f(v.w);
  }
}
__device__ __forceinline__ const void* eoff(const void* p, size_t off, int f) {
  return f ? (const void*)((const float*)p + off) : (const void*)((const u16*)p + off);
}

// dtype probe: bf16 storage -> lower u16 of each word is a sane bf16; f32 -> random mantissa
__global__ void detect_kernel(const unsigned int* __restrict__ w, int* __restrict__ flag) {
  unsigned int x = w[threadIdx.x];
  int e = (x >> 7) & 0xFF;
  int ok = (e >= 97 && e <= 157);
  unsigned long long m = __ballot(ok);
  if (threadIdx.x == 0) flag[0] = (__popcll(m) >= 48) ? 0 : 1;  // 0=bf16, 1=f32
}

// C[M,Nc] = act(A1@B1 + A2@B2 + bias). Row-major, f32 accum.
// 64x64 tile, BK=16, 256 threads, 4x4 microtile.
__global__ __launch_bounds__(256) void gemm2(
    const int* __restrict__ flag,
    const void* __restrict__ A1, int lda1,
    const void* __restrict__ B1b, size_t offB1, int ldb1, int K1, int inA1, int inB1,
    const void* __restrict__ A2, int lda2,
    const void* __restrict__ B2b, size_t offB2, int ldb2, int K2, int inA2, int inB2,
    const void* __restrict__ bias, int inBias,
    void* __restrict__ Cv, int ldc, int Nc, int relu, int c_f32)
{
  const int fin = flag[0];
  __shared__ float As[16][68];
  __shared__ float Bs[16][68];
  const int tid = threadIdx.x;
  const int row0 = blockIdx.y << 6;
  const int col0 = blockIdx.x << 6;
  const int tr = tid >> 4;
  const int tc = tid & 15;
  const int ar = tid >> 2;
  const int ak = (tid & 3) << 2;
  const int bk = tid >> 4;
  const int bc = (tid & 15) << 2;
  float acc[4][4] = {};

  for (int pair = 0; pair < 2; ++pair) {
    const void* A = pair ? A2 : A1;
    if (!A) break;
    const int af = (pair ? inA2 : inA1) ? fin : 0;
    const int bf = (pair ? inB2 : inB1) ? fin : 0;
    const void* B = eoff(pair ? B2b : B1b, pair ? offB2 : offB1, bf);
    const int lda = pair ? lda2 : lda1;
    const int ldb = pair ? ldb2 : ldb1;
    const int K   = pair ? K2 : K1;
    for (int k0 = 0; k0 < K; k0 += 16) {
      float a0 = 0.f, a1 = 0.f, a2 = 0.f, a3 = 0.f;
      if (k0 + ak < K)
        ld4(A, (size_t)(row0 + ar) * lda + k0 + ak, af, a0, a1, a2, a3);
      As[ak + 0][ar] = a0; As[ak + 1][ar] = a1;
      As[ak + 2][ar] = a2; As[ak + 3][ar] = a3;

      float b0 = 0.f, b1 = 0.f, b2 = 0.f, b3 = 0.f;
      if (k0 + bk < K) {
        const size_t bo = (size_t)(k0 + bk) * ldb + col0 + bc;
        const int rem = Nc - (col0 + bc);
        if (rem >= 1) b0 = ld1(B, bo + 0, bf);
        if (rem >= 2) b1 = ld1(B, bo + 1, bf);
        if (rem >= 3) b2 = ld1(B, bo + 2, bf);
        if (rem >= 4) b3 = ld1(B, bo + 3, bf);
      }
      Bs[bk][bc + 0] = b0; Bs[bk][bc + 1] = b1;
      Bs[bk][bc + 2] = b2; Bs[bk][bc + 3] = b3;
      __syncthreads();

      #pragma unroll
      for (int kk = 0; kk < 16; ++kk) {
        const float4 a = *(const float4*)&As[kk][tr << 2];
        const float4 b = *(const float4*)&Bs[kk][tc << 2];
        acc[0][0] = fmaf(a.x, b.x, acc[0][0]);
        acc[0][1] = fmaf(a.x, b.y, acc[0][1]);
        acc[0][2] = fmaf(a.x, b.z, acc[0][2]);
        acc[0][3] = fmaf(a.x, b.w, acc[0][3]);
        acc[1][0] = fmaf(a.y, b.x, acc[1][0]);
        acc[1][1] = fmaf(a.y, b.y, acc[1][1]);
        acc[1][2] = fmaf(a.y, b.z, acc[1][2]);
        acc[1][3] = fmaf(a.y, b.w, acc[1][3]);
        acc[2][0] = fmaf(a.z, b.x, acc[2][0]);
        acc[2][1] = fmaf(a.z, b.y, acc[2][1]);
        acc[2][2] = fmaf(a.z, b.z, acc[2][2]);
        acc[2][3] = fmaf(a.z, b.w, acc[2][3]);
        acc[3][0] = fmaf(a.w, b.x, acc[3][0]);
        acc[3][1] = fmaf(a.w, b.y, acc[3][1]);
        acc[3][2] = fmaf(a.w, b.z, acc[3][2]);
        acc[3][3] = fmaf(a.w, b.w, acc[3][3]);
      }
      __syncthreads();
    }
  }

  #pragma unroll
  for (int i = 0; i < 4; ++i) {
    const int r = row0 + (tr << 2) + i;
    #pragma unroll
    for (int j = 0; j < 4; ++j) {
      const int c = col0 + (tc << 2) + j;
      if (c < Nc) {
        float v = acc[i][j];
        if (bias) v += ld1(bias, c, inBias ? fin : 0);
        if (relu) v = fmaxf(v, 0.f);
        if (c_f32) ((float*)Cv)[(size_t)r * ldc + c] = v;
        else       ((u16*)Cv)[(size_t)r * ldc + c] = f2bf(v);
      }
    }
  }
}

// --- CSR build: degree count -> exclusive scan -> scatter ---
__global__ void cnt_kernel(const int* __restrict__ edst, int* __restrict__ cnt) {
  const int i = blockIdx.x * 256 + threadIdx.x;
  if (i < EE) atomicAdd(&cnt[edst[i]], 1);
}

// single block, 1024 threads, 16 elems/thread; NN = 1024*16
__global__ __launch_bounds__(1024) void scan_kernel(const int* __restrict__ cnt,
                                                    int* __restrict__ offs,
                                                    int* __restrict__ woffs) {
  __shared__ int part[1024];
  const int t = threadIdx.x;
  const int base = t * 16;
  int loc[16];
  int s = 0;
  #pragma unroll
  for (int i = 0; i < 16; ++i) { loc[i] = s; s += cnt[base + i]; }
  part[t] = s;
  __syncthreads();
  for (int off = 1; off < 1024; off <<= 1) {
    int v = (t >= off) ? part[t - off] : 0;
    __syncthreads();
    part[t] += v;
    __syncthreads();
  }
  const int chunk_excl = (t == 0) ? 0 : part[t - 1];
  #pragma unroll
  for (int i = 0; i < 16; ++i) {
    int o = chunk_excl + loc[i];
    offs[base + i] = o;
    woffs[base + i] = o;
  }
  if (t == 1023) offs[NN] = part[1023];
}

__global__ void scatter_kernel(const int* __restrict__ esrc, const int* __restrict__ edst,
                               int* __restrict__ woffs,
                               int* __restrict__ order, int* __restrict__ srcs) {
  const int e = blockIdx.x * 256 + threadIdx.x;
  if (e < EE) {
    const int d = edst[e];
    const int pos = atomicAdd(&woffs[d], 1);
    order[pos] = e;
    srcs[pos] = esrc[e];
  }
}

// appearance aggregation: one block per dst node, no atomics.
// aggn[n] = mean_e relu(P1[src]+P2[n]+s_f[e]@W_es+b_e); W_es cols in registers.
__global__ __launch_bounds__(256) void app_agg(
    const int* __restrict__ flag,
    const u16* __restrict__ P1, const u16* __restrict__ P2,
    const void* __restrict__ s_f, const void* __restrict__ W_eb,
    const void* __restrict__ b_e,
    const int* __restrict__ offs, const int* __restrict__ order,
    const int* __restrict__ srcs, u16* __restrict__ aggn)
{
  const int fin = flag[0];
  const int n = blockIdx.x;
  const int tid = threadIdx.x;
  const int c4 = tid << 2;
  const void* W_es = eoff(W_eb, (size_t)2 * DF * DF, fin);

  float wx[16], wy[16], wz[16], ww[16];
  #pragma unroll
  for (int k = 0; k < 16; ++k)
    ld4(W_es, (size_t)k * DF + c4, fin, wx[k], wy[k], wz[k], ww[k]);

  float be0, be1, be2, be3;
  ld4(b_e, c4, fin, be0, be1, be2, be3);
  const ushort4 p2 = *(const ushort4*)(P2 + (size_t)n * DF + c4);
  const float base0 = bf2f(p2.x) + be0;
  const float base1 = bf2f(p2.y) + be1;
  const float base2 = bf2f(p2.z) + be2;
  const float base3 = bf2f(p2.w) + be3;

  const int beg = offs[n], end = offs[n + 1];
  float a0 = 0.f, a1 = 0.f, a2 = 0.f, a3 = 0.f;
  for (int j = beg; j < end; ++j) {
    const int e = order[j];
    const int s = srcs[j];
    float sf[16];
    #pragma unroll
    for (int k = 0; k < 16; ++k) sf[k] = ld1(s_f, (size_t)e * DS + k, fin);
    const ushort4 p1 = *(const ushort4*)(P1 + (size_t)s * DF + c4);
    float v0 = bf2f(p1.x) + base0;
    float v1 = bf2f(p1.y) + base1;
    float v2 = bf2f(p1.z) + base2;
    float v3 = bf2f(p1.w) + base3;
    #pragma unroll
    for (int k = 0; k < 16; ++k) {
      v0 = fmaf(sf[k], wx[k], v0);
      v1 = fmaf(sf[k], wy[k], v1);
      v2 = fmaf(sf[k], wz[k], v2);
      v3 = fmaf(sf[k], ww[k], v3);
    }
    a0 += fmaxf(v0, 0.f); a1 += fmaxf(v1, 0.f);
    a2 += fmaxf(v2, 0.f); a3 += fmaxf(v3, 0.f);
  }
  const float inv = 1.f / fmaxf((float)(end - beg), 1.f);
  ushort4 o;
  o.x = f2bf(a0 * inv); o.y = f2bf(a1 * inv);
  o.z = f2bf(a2 * inv); o.w = f2bf(a3 * inv);
  *(ushort4*)(aggn + (size_t)n * DF + c4) = o;
}

// language aggregation: one block per dst node.
__global__ __launch_bounds__(320) void lang_agg(
    const int* __restrict__ flag,
    const u16* __restrict__ Q1, const u16* __restrict__ Q2,
    const void* __restrict__ b_el,
    const int* __restrict__ offs, const int* __restrict__ srcs,
    u16* __restrict__ aggln)
{
  const int fin = flag[0];
  const int n = blockIdx.x;
  const int c = threadIdx.x;
  if (c >= DL) return;
  const float base = bf2f(Q2[(size_t)n * DL + c]) + ld1(b_el, c, fin);
  const int beg = offs[n], end = offs[n + 1];
  float a = 0.f;
  for (int j = beg; j < end; ++j) {
    const int s = srcs[j];
    a += fmaxf(bf2f(Q1[(size_t)s * DL + c]) + base, 0.f);
  }
  aggln[(size_t)n * DL + c] = f2bf(a / fmaxf((float)(end - beg), 1.f));
}

// pred[e] = Rd[dst] + Rs[src] + s_f_ro[e]@Wp_s + b_p ; 8 edges per block
__global__ __launch_bounds__(128) void readout_kernel(
    const int* __restrict__ flag,
    const float* __restrict__ Rd, const float* __restrict__ Rs,
    const void* __restrict__ s_f_ro,
    const void* __restrict__ W_pb, size_t offWps,
    const void* __restrict__ b_p,
    const int* __restrict__ rsrc, const int* __restrict__ rdst, void* __restrict__ out)
{
  const int fin = flag[0];
  __shared__ float wps[16 * NC];
  const void* Wp_s = eoff(W_pb, offWps, fin);
  const int tid = threadIdx.x;
  for (int i = tid; i < 16 * NC; i += 128) wps[i] = ld1(Wp_s, i, fin);
  __syncthreads();
  const float bp = (tid < NC) ? ld1(b_p, tid, fin) : 0.f;

  const int e0 = blockIdx.x << 3;
  for (int ee = 0; ee < 8; ++ee) {
    const int e = e0 + ee;
    const int s = rsrc[e];
    const int d = rdst[e];
    if (tid < NC) {
      float acc = Rd[(size_t)d * NC + tid] + Rs[(size_t)s * NC + tid] + bp;
      #pragma unroll
      for (int k = 0; k < 16; ++k)
        acc = fmaf(ld1(s_f_ro, (size_t)e * DS + k, fin), wps[k * NC + tid], acc);
      if (fin) ((float*)out)[(size_t)e * NC + tid] = acc;
      else     ((u16*)out)[(size_t)e * NC + tid] = f2bf(acc);
    }
  }
}

extern "C" void kernel_launch(void* const* d_in, const int* in_sizes, int n_in,
                              void* d_out, int out_size, void* d_ws, size_t ws_size,
                              hipStream_t stream)
{
  const void* feat  = d_in[0];
  const void* w2v   = d_in[1];
  const void* s_f   = d_in[2];
  const void* s_fro = d_in[3];
  const void* W_e   = d_in[4];
  const void* b_e   = d_in[5];
  const void* W_el  = d_in[6];
  const void* b_el  = d_in[7];
  const void* W_nu  = d_in[8];
  const void* b_nu  = d_in[9];
  const void* W_nul = d_in[10];
  const void* b_nul = d_in[11];
  const void* W_p   = d_in[12];
  const void* b_p   = d_in[13];
  const int* esrc  = (const int*)d_in[14];
  const int* edst  = (const int*)d_in[15];
  const int* rsrc  = (const int*)d_in[16];
  const int* rdst  = (const int*)d_in[17];

  // workspace layout; peak ~127 MB
  char* ws = (char*)d_ws;
  int*   flag  = (int*)ws;                          // 256 B slot
  int*   cnt   = (int*)(ws + 256);                  // NN
  int*   offs  = cnt + NN;                          // NN+1
  int*   woffs = offs + NN + 1;                     // NN
  int*   order = woffs + NN;                        // EE
  int*   srcs  = order + EE;                        // EE
  u16*   P1    = (u16*)(srcs + EE);                 // NN*DF bf16 (32 MB)
  u16*   P2    = P1 + (size_t)NN * DF;              // 32 MB
  u16*   Q1    = P2 + (size_t)NN * DF;              // 9.8 MB
  u16*   Q2    = Q1 + (size_t)NN * DL;              // 9.8 MB
  u16*   aggn  = Q2 + (size_t)NN * DL;              // 32 MB
  u16*   aggln = aggn + (size_t)NN * DF;            // 9.8 MB
  // aliases (stream-ordered): P1/Q1 dead after agg kernels; P2 dead too
  u16*   newf = P1;
  u16*   newl = Q1;
  float* Rd   = (float*)P2;                         // NN*NC f32 (7.7 MB)
  float* Rs   = Rd + (size_t)NN * NC;               // 7.7 MB (fits in P2's 32 MB)

  detect_kernel<<<1, 64, 0, stream>>>((const unsigned int*)feat, flag);
  hipMemsetAsync(cnt, 0, (size_t)NN * 4, stream);
  cnt_kernel<<<EE / 256, 256, 0, stream>>>(edst, cnt);
  scan_kernel<<<1, 1024, 0, stream>>>(cnt, offs, woffs);
  scatter_kernel<<<EE / 256, 256, 0, stream>>>(esrc, edst, woffs, order, srcs);

  dim3 gF(DF / 64, NN / 64);            // (16,256)
  dim3 gL((DL + 63) / 64, NN / 64);     // (5,256)
  dim3 gC((NC + 63) / 64, NN / 64);     // (2,256)

  // node-level projections for the edge MLPs
  gemm2<<<gF, 256, 0, stream>>>(flag, feat, DF, W_e, 0,                 DF, DF, 1, 1,
                                nullptr, 0, nullptr, 0, 0, 0, 0, 0,
                                nullptr, 0, P1, DF, DF, 0, 0);
  gemm2<<<gF, 256, 0, stream>>>(flag, feat, DF, W_e, (size_t)DF * DF,   DF, DF, 1, 1,
                                nullptr, 0, nullptr, 0, 0, 0, 0, 0,
                                nullptr, 0, P2, DF, DF, 0, 0);
  gemm2<<<gL, 256, 0, stream>>>(flag, w2v, DL, W_el, 0,                 DL, DL, 1, 1,
                                nullptr, 0, nullptr, 0, 0, 0, 0, 0,
                                nullptr, 0, Q1, DL, DL, 0, 0);
  gemm2<<<gL, 256, 0, stream>>>(flag, w2v, DL, W_el, (size_t)DL * DL,   DL, DL, 1, 1,
                                nullptr, 0, nullptr, 0, 0, 0, 0, 0,
                                nullptr, 0, Q2, DL, DL, 0, 0);

  // CSR-grouped mean aggregation (no atomics)
  app_agg<<<NN, 256, 0, stream>>>(flag, P1, P2, s_f, W_e, b_e,
                                  offs, order, srcs, aggn);
  lang_agg<<<NN, 320, 0, stream>>>(flag, Q1, Q2, b_el, offs, srcs, aggln);

  // node updates
  gemm2<<<gF, 256, 0, stream>>>(flag, feat, DF, W_nu, 0,                DF, DF, 1, 1,
                                aggn, DF, W_nu, (size_t)DF * DF,        DF, DF, 0, 1,
                                b_nu, 1, newf, DF, DF, 1, 0);
  gemm2<<<gL, 256, 0, stream>>>(flag, w2v, DL, W_nul, 0,                DL, DL, 1, 1,
                                aggln, DL, W_nul, (size_t)DL * DL,      DL, DL, 0, 1,
                                b_nul, 1, newl, DL, DL, 1, 0);

  // node-level readout projections (f32 out)
  gemm2<<<gC, 256, 0, stream>>>(flag, newf, DF, W_p, 0,                 NC, DF, 0, 1,
                                newl, DL, W_p, (size_t)DF * NC,         NC, DL, 0, 1,
                                nullptr, 0, Rd, NC, NC, 0, 1);
  gemm2<<<gC, 256, 0, stream>>>(flag, newl, DL, W_p, (size_t)(DF + DL + DS) * NC,      NC, DL, 0, 1,
                                newf, DF, W_p, (size_t)(DF + DL + DS + DL) * NC,       NC, DF, 0, 1,
                                nullptr, 0, Rs, NC, NC, 0, 1);

  readout_kernel<<<ERO / 8, 128, 0, stream>>>(flag, Rd, Rs, s_fro,
                                              W_p, (size_t)(DF + DL) * NC, b_p,
                                              rsrc, rdst, d_out);
}

// Round 4
// 1180.848 us; speedup vs baseline: 3.9124x; 2.3973x over previous
//
#include <hip/hip_runtime.h>

typedef unsigned short u16;
typedef __attribute__((ext_vector_type(8))) short short8;
typedef __attribute__((ext_vector_type(4))) float f32x4;

#define NN 16384   // nodes
#define EE 131072  // edges
#define ERO 32768  // readout edges
#define DF 1024    // appearance dim
#define DL 300     // word2vec dim
#define DLP 320    // K-padded language dim (mult of 32)
#define DLN 384    // N-padded language B^T storage rows (3 tiles of 128)
#define DS 16      // spatial dim
#define NC 117     // classes
#define NCP 128    // padded classes

__device__ __forceinline__ float bf2f(u16 x) {
  unsigned int u = ((unsigned int)x) << 16;
  float f;
  __builtin_memcpy(&f, &u, 4);
  return f;
}
__device__ __forceinline__ u16 f2bf(float f) {
  unsigned int u;
  __builtin_memcpy(&u, &f, 4);
  u = (u + 0x7FFFu + ((u >> 16) & 1u)) >> 16;
  return (u16)u;
}
__device__ __forceinline__ float ld1(const void* p, size_t i, int f) {
  return f ? ((const float*)p)[i] : bf2f(((const u16*)p)[i]);
}
__device__ __forceinline__ void ld4(const void* p, size_t i, int f,
                                    float& x, float& y, float& z, float& w) {
  if (f) {
    float4 v = *(const float4*)((const float*)p + i);
    x = v.x; y = v.y; z = v.z; w = v.w;
  } else {
    ushort4 v = *(const ushort4*)((const u16*)p + i);
    x = bf2f(v.x); y = bf2f(v.y); z = bf2f(v.z); w = bf2f(v.w);
  }
}
__device__ __forceinline__ const void* eoff(const void* p, size_t off, int f) {
  return f ? (const void*)((const float*)p + off) : (const void*)((const u16*)p + off);
}

// dtype probe (round-1 learning: harness stores float tensors as f32 here)
__global__ void detect_kernel(const unsigned int* __restrict__ w, int* __restrict__ flag) {
  unsigned int x = w[threadIdx.x];
  int e = (x >> 7) & 0xFF;
  int ok = (e >= 97 && e <= 157);
  unsigned long long m = __ballot(ok);
  if (threadIdx.x == 0) flag[0] = (__popcll(m) >= 48) ? 0 : 1;  // 0=bf16, 1=f32
}

// W [Kreal][Nreal] (row stride Nstride, element offset off, dtype per flag)
// -> out bf16 [Np][Kp] = W^T zero-padded
__global__ void transpose_w(const int* __restrict__ flag, const void* __restrict__ W,
                            size_t off, int Kreal, int Nreal, int Nstride,
                            u16* __restrict__ out, int Kp, int Np) {
  const int idx = blockIdx.x * 256 + threadIdx.x;
  if (idx >= Np * Kp) return;
  const int n = idx / Kp, k = idx % Kp;
  float v = 0.f;
  if (k < Kreal && n < Nreal) v = ld1(W, off + (size_t)k * Nstride + n, flag[0]);
  out[idx] = f2bf(v);
}

// ---- MFMA GEMM: C[M, N] = act(A1@B1^T + A2@B2^T + bias) ----
// 128x128 block tile, BK=32, 256 thr = 4 waves (2x2 of 64x64), 16x16x32 bf16 MFMA.
// B^T is bf16 [gridN*128][Kpad] (pre-transposed, zero-padded).
// AM: 0 = A is bf16 [M][lda>=Kpad] staged via global_load_lds(16B);
//     1 = A is f32  [M][lda] staged manually with k<Kreal bound (pad zeros).

// bf16 async stage of a 128x32 tile: LDS row-major [128][32] u16, per-wave 2 issues.
__device__ __forceinline__ void stage_bf16_async(const u16* __restrict__ G, size_t rbase,
                                                 int lda, int k0, u16* lds, int w, int lane) {
  #pragma unroll
  for (int t = 0; t < 2; ++t) {
    const int rr = (w << 5) + (t << 4) + (lane >> 2);
    const u16* gp = G + (rbase + rr) * (size_t)lda + k0 + ((lane & 3) << 3);
    __builtin_amdgcn_global_load_lds(
        (const __attribute__((address_space(1))) void*)gp,
        (__attribute__((address_space(3))) void*)(lds + (((w << 5) + (t << 4)) * 32)),
        16, 0, 0);
  }
}

__device__ __forceinline__ void stage_f32_manual(const float* __restrict__ G, int row0,
                                                 int lda, int k0, int Kreal,
                                                 u16* lds, int tid) {
  const int r = tid >> 1, half = tid & 1;
  const float* gp = G + (size_t)(row0 + r) * lda + k0 + (half << 4);
  #pragma unroll
  for (int qq = 0; qq < 4; ++qq) {
    const int kk = k0 + (half << 4) + (qq << 2);
    float4 v = make_float4(0.f, 0.f, 0.f, 0.f);
    if (kk < Kreal) v = *(const float4*)(gp + (qq << 2));
    ushort4 o;
    o.x = f2bf(v.x); o.y = f2bf(v.y); o.z = f2bf(v.z); o.w = f2bf(v.w);
    *(ushort4*)(lds + r * 32 + (half << 4) + (qq << 2)) = o;
  }
}

template <int AM>
__device__ __forceinline__ void kloop(const void* __restrict__ A, int lda, int Kreal, int Kpad,
                                      const u16* __restrict__ B, u16* As, u16* Bs,
                                      f32x4 (&acc)[4][4], int row0, int col0,
                                      int tid, int lane, int w, int wm, int wn, int ml, int q) {
  for (int k0 = 0; k0 < Kpad; k0 += 32) {
    if (AM == 0) stage_bf16_async((const u16*)A, (size_t)row0, lda, k0, As, w, lane);
    else         stage_f32_manual((const float*)A, row0, lda, k0, Kreal, As, tid);
    stage_bf16_async(B, (size_t)col0, Kpad, k0, Bs, w, lane);
    __syncthreads();
    short8 af[4], bfr[4];
    #pragma unroll
    for (int i = 0; i < 4; ++i)
      af[i] = *(const short8*)(As + ((wm << 6) + (i << 4) + ml) * 32 + (q << 3));
    #pragma unroll
    for (int j = 0; j < 4; ++j)
      bfr[j] = *(const short8*)(Bs + ((wn << 6) + (j << 4) + ml) * 32 + (q << 3));
    #pragma unroll
    for (int i = 0; i < 4; ++i)
      #pragma unroll
      for (int j = 0; j < 4; ++j)
        acc[i][j] = __builtin_amdgcn_mfma_f32_16x16x32_bf16(af[i], bfr[j], acc[i][j], 0, 0, 0);
    __syncthreads();
  }
}

template <int AM1, int AM2>
__global__ __launch_bounds__(256) void mfma_bt(
    const int* __restrict__ flag,
    const void* __restrict__ A1, int lda1, int K1real, int K1pad, const u16* __restrict__ B1,
    const void* __restrict__ A2, int lda2, int K2real, int K2pad, const u16* __restrict__ B2,
    const void* __restrict__ bias, int inBias,
    void* __restrict__ Cv, int ldc, int Nreal, int Npad, int relu, int cf32)
{
  __shared__ __attribute__((aligned(16))) u16 As[128 * 32];
  __shared__ __attribute__((aligned(16))) u16 Bs[128 * 32];
  const int tid = threadIdx.x;
  const int lane = tid & 63;
  const int w = tid >> 6;
  const int wm = w >> 1, wn = w & 1;
  const int row0 = blockIdx.y << 7;
  const int col0 = blockIdx.x << 7;
  const int ml = lane & 15, q = lane >> 4;

  f32x4 acc[4][4];
  #pragma unroll
  for (int i = 0; i < 4; ++i)
    #pragma unroll
    for (int j = 0; j < 4; ++j) {
      f32x4 z = {0.f, 0.f, 0.f, 0.f};
      acc[i][j] = z;
    }

  kloop<AM1>(A1, lda1, K1real, K1pad, B1, As, Bs, acc, row0, col0, tid, lane, w, wm, wn, ml, q);
  if constexpr (AM2 >= 0)
    kloop<AM2>(A2, lda2, K2real, K2pad, B2, As, Bs, acc, row0, col0, tid, lane, w, wm, wn, ml, q);

  const int fin = flag[0];
  // C/D layout (m89-verified): col = lane&15, row = (lane>>4)*4 + reg
  #pragma unroll
  for (int j = 0; j < 4; ++j) {
    const int col = col0 + (wn << 6) + (j << 4) + ml;
    if (col >= Npad) continue;
    float bv = 0.f;
    if (bias && col < Nreal) bv = ld1(bias, col, inBias ? fin : 0);
    #pragma unroll
    for (int i = 0; i < 4; ++i) {
      #pragma unroll
      for (int r = 0; r < 4; ++r) {
        const int row = row0 + (wm << 6) + (i << 4) + (q << 2) + r;
        float v = 0.f;
        if (col < Nreal) {
          v = acc[i][j][r] + bv;
          if (relu) v = fmaxf(v, 0.f);
        }
        if (cf32) ((float*)Cv)[(size_t)row * ldc + col] = v;
        else      ((u16*)Cv)[(size_t)row * ldc + col] = f2bf(v);
      }
    }
  }
}

// --- CSR build ---
__global__ void cnt_kernel(const int* __restrict__ edst, int* __restrict__ cnt) {
  const int i = blockIdx.x * 256 + threadIdx.x;
  if (i < EE) atomicAdd(&cnt[edst[i]], 1);
}

__global__ __launch_bounds__(1024) void scan_kernel(const int* __restrict__ cnt,
                                                    int* __restrict__ offs,
                                                    int* __restrict__ woffs) {
  __shared__ int part[1024];
  const int t = threadIdx.x;
  const int base = t * 16;
  int loc[16];
  int s = 0;
  #pragma unroll
  for (int i = 0; i < 16; ++i) { loc[i] = s; s += cnt[base + i]; }
  part[t] = s;
  __syncthreads();
  for (int off = 1; off < 1024; off <<= 1) {
    int v = (t >= off) ? part[t - off] : 0;
    __syncthreads();
    part[t] += v;
    __syncthreads();
  }
  const int chunk_excl = (t == 0) ? 0 : part[t - 1];
  #pragma unroll
  for (int i = 0; i < 16; ++i) {
    int o = chunk_excl + loc[i];
    offs[base + i] = o;
    woffs[base + i] = o;
  }
  if (t == 1023) offs[NN] = part[1023];
}

__global__ void scatter_kernel(const int* __restrict__ esrc, const int* __restrict__ edst,
                               int* __restrict__ woffs,
                               int* __restrict__ order, int* __restrict__ srcs) {
  const int e = blockIdx.x * 256 + threadIdx.x;
  if (e < EE) {
    const int d = edst[e];
    const int pos = atomicAdd(&woffs[d], 1);
    order[pos] = e;
    srcs[pos] = esrc[e];
  }
}

// appearance aggregation: one block per dst node, no atomics.
__global__ __launch_bounds__(256) void app_agg(
    const int* __restrict__ flag,
    const u16* __restrict__ P1, const u16* __restrict__ P2,
    const void* __restrict__ s_f, const void* __restrict__ W_eb,
    const void* __restrict__ b_e,
    const int* __restrict__ offs, const int* __restrict__ order,
    const int* __restrict__ srcs, u16* __restrict__ aggn)
{
  const int fin = flag[0];
  const int n = blockIdx.x;
  const int tid = threadIdx.x;
  const int c4 = tid << 2;
  const void* W_es = eoff(W_eb, (size_t)2 * DF * DF, fin);

  float wx[16], wy[16], wz[16], ww[16];
  #pragma unroll
  for (int k = 0; k < 16; ++k)
    ld4(W_es, (size_t)k * DF + c4, fin, wx[k], wy[k], wz[k], ww[k]);

  float be0, be1, be2, be3;
  ld4(b_e, c4, fin, be0, be1, be2, be3);
  const ushort4 p2 = *(const ushort4*)(P2 + (size_t)n * DF + c4);
  const float base0 = bf2f(p2.x) + be0;
  const float base1 = bf2f(p2.y) + be1;
  const float base2 = bf2f(p2.z) + be2;
  const float base3 = bf2f(p2.w) + be3;

  const int beg = offs[n], end = offs[n + 1];
  float a0 = 0.f, a1 = 0.f, a2 = 0.f, a3 = 0.f;
  for (int j = beg; j < end; ++j) {
    const int e = order[j];
    const int s = srcs[j];
    float sf[16];
    #pragma unroll
    for (int k = 0; k < 16; ++k) sf[k] = ld1(s_f, (size_t)e * DS + k, fin);
    const ushort4 p1 = *(const ushort4*)(P1 + (size_t)s * DF + c4);
    float v0 = bf2f(p1.x) + base0;
    float v1 = bf2f(p1.y) + base1;
    float v2 = bf2f(p1.z) + base2;
    float v3 = bf2f(p1.w) + base3;
    #pragma unroll
    for (int k = 0; k < 16; ++k) {
      v0 = fmaf(sf[k], wx[k], v0);
      v1 = fmaf(sf[k], wy[k], v1);
      v2 = fmaf(sf[k], wz[k], v2);
      v3 = fmaf(sf[k], ww[k], v3);
    }
    a0 += fmaxf(v0, 0.f); a1 += fmaxf(v1, 0.f);
    a2 += fmaxf(v2, 0.f); a3 += fmaxf(v3, 0.f);
  }
  const float inv = 1.f / fmaxf((float)(end - beg), 1.f);
  ushort4 o;
  o.x = f2bf(a0 * inv); o.y = f2bf(a1 * inv);
  o.z = f2bf(a2 * inv); o.w = f2bf(a3 * inv);
  *(ushort4*)(aggn + (size_t)n * DF + c4) = o;
}

// language aggregation: one block per dst node; output [NN][DLP] zero-padded
__global__ __launch_bounds__(320) void lang_agg(
    const int* __restrict__ flag,
    const u16* __restrict__ Q1, const u16* __restrict__ Q2,
    const void* __restrict__ b_el,
    const int* __restrict__ offs, const int* __restrict__ srcs,
    u16* __restrict__ aggln)
{
  const int fin = flag[0];
  const int n = blockIdx.x;
  const int c = threadIdx.x;
  if (c >= DL) { aggln[(size_t)n * DLP + c] = 0; return; }
  const float base = bf2f(Q2[(size_t)n * DL + c]) + ld1(b_el, c, fin);
  const int beg = offs[n], end = offs[n + 1];
  float a = 0.f;
  for (int j = beg; j < end; ++j) {
    const int s = srcs[j];
    a += fmaxf(bf2f(Q1[(size_t)s * DL + c]) + base, 0.f);
  }
  aggln[(size_t)n * DLP + c] = f2bf(a / fmaxf((float)(end - beg), 1.f));
}

// pred[e] = Rd[dst] + Rs[src] + s_f_ro[e]@Wp_s + b_p ; Rd/Rs stride NCP
__global__ __launch_bounds__(128) void readout_kernel(
    const int* __restrict__ flag,
    const float* __restrict__ Rd, const float* __restrict__ Rs,
    const void* __restrict__ s_f_ro,
    const void* __restrict__ W_pb, size_t offWps,
    const void* __restrict__ b_p,
    const int* __restrict__ rsrc, const int* __restrict__ rdst, void* __restrict__ out)
{
  const int fin = flag[0];
  __shared__ float wps[16 * NC];
  const void* Wp_s = eoff(W_pb, offWps, fin);
  const int tid = threadIdx.x;
  for (int i = tid; i < 16 * NC; i += 128) wps[i] = ld1(Wp_s, i, fin);
  __syncthreads();
  const float bp = (tid < NC) ? ld1(b_p, tid, fin) : 0.f;

  const int e0 = blockIdx.x << 3;
  for (int ee = 0; ee < 8; ++ee) {
    const int e = e0 + ee;
    const int s = rsrc[e];
    const int d = rdst[e];
    if (tid < NC) {
      float acc = Rd[(size_t)d * NCP + tid] + Rs[(size_t)s * NCP + tid] + bp;
      #pragma unroll
      for (int k = 0; k < 16; ++k)
        acc = fmaf(ld1(s_f_ro, (size_t)e * DS + k, fin), wps[k * NC + tid], acc);
      if (fin) ((float*)out)[(size_t)e * NC + tid] = acc;
      else     ((u16*)out)[(size_t)e * NC + tid] = f2bf(acc);
    }
  }
}

extern "C" void kernel_launch(void* const* d_in, const int* in_sizes, int n_in,
                              void* d_out, int out_size, void* d_ws, size_t ws_size,
                              hipStream_t stream)
{
  const void* feat  = d_in[0];
  const void* w2v   = d_in[1];
  const void* s_f   = d_in[2];
  const void* s_fro = d_in[3];
  const void* W_e   = d_in[4];
  const void* b_e   = d_in[5];
  const void* W_el  = d_in[6];
  const void* b_el  = d_in[7];
  const void* W_nu  = d_in[8];
  const void* b_nu  = d_in[9];
  const void* W_nul = d_in[10];
  const void* b_nul = d_in[11];
  const void* W_p   = d_in[12];
  const void* b_p   = d_in[13];
  const int* esrc  = (const int*)d_in[14];
  const int* edst  = (const int*)d_in[15];
  const int* rsrc  = (const int*)d_in[16];
  const int* rdst  = (const int*)d_in[17];

  // ---- workspace layout (~122 MB, aliased regions) ----
  char* p = (char*)d_ws;
  int* flag  = (int*)p; p += 256;
  int* cnt   = (int*)p; p += (size_t)NN * 4;
  int* offs  = (int*)p; p += (size_t)(NN + 64) * 4;
  int* woffs = (int*)p; p += (size_t)NN * 4;
  int* order = (int*)p; p += (size_t)EE * 4;
  int* srcs  = (int*)p; p += (size_t)EE * 4;
  u16* We1T   = (u16*)p; p += (size_t)DF * DF * 2;
  u16* We2T   = (u16*)p; p += (size_t)DF * DF * 2;
  u16* Wnu1T  = (u16*)p; p += (size_t)DF * DF * 2;
  u16* Wnu2T  = (u16*)p; p += (size_t)DF * DF * 2;
  u16* Wel1T  = (u16*)p; p += (size_t)DLN * DLP * 2;
  u16* Wel2T  = (u16*)p; p += (size_t)DLN * DLP * 2;
  u16* Wnul1T = (u16*)p; p += (size_t)DLN * DLP * 2;
  u16* Wnul2T = (u16*)p; p += (size_t)DLN * DLP * 2;
  u16* WpdFT  = (u16*)p; p += (size_t)NCP * DF * 2;
  u16* WpsFT  = (u16*)p; p += (size_t)NCP * DF * 2;
  u16* WpdLT  = (u16*)p; p += (size_t)NCP * DLP * 2;
  u16* WpsLT  = (u16*)p; p += (size_t)NCP * DLP * 2;
  u16* regionC = (u16*)p; p += (size_t)NN * DF * 2;   // Q1,Q2,aggln -> P1 -> newf
  u16* newl    = (u16*)p; p += (size_t)NN * DLP * 2;
  u16* regionD = (u16*)p; p += (size_t)NN * DF * 2;   // P2 -> Rd,Rs
  u16* aggn    = (u16*)p; p += (size_t)NN * DF * 2;
  // aliases (stream-ordered lifetimes, see launch order)
  u16* Q1    = regionC;
  u16* Q2    = regionC + (size_t)NN * DL;
  u16* aggln = regionC + (size_t)2 * NN * DL;
  u16* P1    = regionC;
  u16* newf  = regionC;
  u16* P2    = regionD;
  float* Rd  = (float*)regionD;
  float* Rs  = Rd + (size_t)NN * NCP;

  detect_kernel<<<1, 64, 0, stream>>>((const unsigned int*)feat, flag);
  hipMemsetAsync(cnt, 0, (size_t)NN * 4, stream);
  cnt_kernel<<<EE / 256, 256, 0, stream>>>(edst, cnt);
  scan_kernel<<<1, 1024, 0, stream>>>(cnt, offs, woffs);
  scatter_kernel<<<EE / 256, 256, 0, stream>>>(esrc, edst, woffs, order, srcs);

  // ---- weight transposes (bf16, zero-padded) ----
  auto T = [&](const void* W, size_t off, int Kr, int Nr, int Nstr, u16* out, int Kp, int Np) {
    transpose_w<<<(Np * Kp + 255) / 256, 256, 0, stream>>>(flag, W, off, Kr, Nr, Nstr, out, Kp, Np);
  };
  T(W_e,   0,                   DF, DF, DF, We1T,  DF, DF);
  T(W_e,   (size_t)DF * DF,     DF, DF, DF, We2T,  DF, DF);
  T(W_nu,  0,                   DF, DF, DF, Wnu1T, DF, DF);
  T(W_nu,  (size_t)DF * DF,     DF, DF, DF, Wnu2T, DF, DF);
  T(W_el,  0,                   DL, DL, DL, Wel1T,  DLP, DLN);
  T(W_el,  (size_t)DL * DL,     DL, DL, DL, Wel2T,  DLP, DLN);
  T(W_nul, 0,                   DL, DL, DL, Wnul1T, DLP, DLN);
  T(W_nul, (size_t)DL * DL,     DL, DL, DL, Wnul2T, DLP, DLN);
  T(W_p,   0,                          DF, NC, NC, WpdFT, DF,  NCP);
  T(W_p,   (size_t)DF * NC,            DL, NC, NC, WpdLT, DLP, NCP);
  T(W_p,   (size_t)(DF + DL + DS) * NC, DL, NC, NC, WpsLT, DLP, NCP);
  T(W_p,   (size_t)(DF + DL + DS + DL) * NC, DF, NC, NC, WpsFT, DF, NCP);

  const dim3 gF(DF / 128, NN / 128);   // (8,128)
  const dim3 gL(DLN / 128, NN / 128);  // (3,128)
  const dim3 gC(1, NN / 128);          // (1,128)

  // ---- language stream ----
  mfma_bt<1, -1><<<gL, 256, 0, stream>>>(flag, w2v, DL, DL, DLP, Wel1T,
                                         nullptr, 0, 0, 0, nullptr,
                                         nullptr, 0, Q1, DL, DL, DL, 0, 0);
  mfma_bt<1, -1><<<gL, 256, 0, stream>>>(flag, w2v, DL, DL, DLP, Wel2T,
                                         nullptr, 0, 0, 0, nullptr,
                                         nullptr, 0, Q2, DL, DL, DL, 0, 0);
  lang_agg<<<NN, DLP, 0, stream>>>(flag, Q1, Q2, b_el, offs, srcs, aggln);
  mfma_bt<1, 0><<<gL, 256, 0, stream>>>(flag, w2v, DL, DL, DLP, Wnul1T,
                                        aggln, DLP, DLP, DLP, Wnul2T,
                                        b_nul, 1, newl, DLP, DL, DLP, 1, 0);
  // ---- appearance stream ----
  mfma_bt<1, -1><<<gF, 256, 0, stream>>>(flag, feat, DF, DF, DF, We1T,
                                         nullptr, 0, 0, 0, nullptr,
                                         nullptr, 0, P1, DF, DF, DF, 0, 0);
  mfma_bt<1, -1><<<gF, 256, 0, stream>>>(flag, feat, DF, DF, DF, We2T,
                                         nullptr, 0, 0, 0, nullptr,
                                         nullptr, 0, P2, DF, DF, DF, 0, 0);
  app_agg<<<NN, 256, 0, stream>>>(flag, P1, P2, s_f, W_e, b_e, offs, order, srcs, aggn);
  mfma_bt<1, 0><<<gF, 256, 0, stream>>>(flag, feat, DF, DF, DF, Wnu1T,
                                        aggn, DF, DF, DF, Wnu2T,
                                        b_nu, 1, newf, DF, DF, DF, 1, 0);
  // ---- readout projections (f32 out, stride NCP) ----
  mfma_bt<0, 0><<<gC, 256, 0, stream>>>(flag, newf, DF, DF, DF, WpdFT,
                                        newl, DLP, DLP, DLP, WpdLT,
                                        nullptr, 0, Rd, NCP, NC, NC, 0, 1);
  mfma_bt<0, 0><<<gC, 256, 0, stream>>>(flag, newl, DLP, DLP, DLP, WpsLT,
                                        newf, DF, DF, DF, WpsFT,
                                        nullptr, 0, Rs, NCP, NC, NC, 0, 1);

  readout_kernel<<<ERO / 8, 128, 0, stream>>>(flag, Rd, Rs, s_fro,
                                              W_p, (size_t)(DF + DL) * NC, b_p,
                                              rsrc, rdst, d_out);
}

// Round 5
// 793.243 us; speedup vs baseline: 5.8242x; 1.4886x over previous
//
#include <hip/hip_runtime.h>

typedef unsigned short u16;
typedef __attribute__((ext_vector_type(8))) short short8;
typedef __attribute__((ext_vector_type(4))) float f32x4;

#define NN 16384   // nodes
#define EE 131072  // edges
#define ERO 32768  // readout edges
#define DF 1024    // appearance dim
#define DL 300     // word2vec dim
#define DLP 320    // K-padded language dim (mult of 32)
#define DLN 384    // N-padded language B^T storage rows (3 tiles of 128)
#define DS 16      // spatial dim
#define NC 117     // classes
#define NCP 128    // padded classes

__device__ __forceinline__ float bf2f(u16 x) {
  unsigned int u = ((unsigned int)x) << 16;
  float f;
  __builtin_memcpy(&f, &u, 4);
  return f;
}
__device__ __forceinline__ u16 f2bf(float f) {
  unsigned int u;
  __builtin_memcpy(&u, &f, 4);
  u = (u + 0x7FFFu + ((u >> 16) & 1u)) >> 16;
  return (u16)u;
}
__device__ __forceinline__ float ld1(const void* p, size_t i, int f) {
  return f ? ((const float*)p)[i] : bf2f(((const u16*)p)[i]);
}
__device__ __forceinline__ void ld4(const void* p, size_t i, int f,
                                    float& x, float& y, float& z, float& w) {
  if (f) {
    float4 v = *(const float4*)((const float*)p + i);
    x = v.x; y = v.y; z = v.z; w = v.w;
  } else {
    ushort4 v = *(const ushort4*)((const u16*)p + i);
    x = bf2f(v.x); y = bf2f(v.y); z = bf2f(v.z); w = bf2f(v.w);
  }
}
__device__ __forceinline__ const void* eoff(const void* p, size_t off, int f) {
  return f ? (const void*)((const float*)p + off) : (const void*)((const u16*)p + off);
}

// dtype probe (measured: f32 on this harness; kept adaptive for safety)
__global__ void detect_kernel(const unsigned int* __restrict__ w, int* __restrict__ flag) {
  unsigned int x = w[threadIdx.x];
  int e = (x >> 7) & 0xFF;
  int ok = (e >= 97 && e <= 157);
  unsigned long long m = __ballot(ok);
  if (threadIdx.x == 0) flag[0] = (__popcll(m) >= 48) ? 0 : 1;  // 0=bf16, 1=f32
}

// contiguous cast to bf16, 8 elems/thread
__global__ void cast_bf16(const int* __restrict__ flag, const void* __restrict__ src,
                          u16* __restrict__ dst, int total8) {
  const int i = blockIdx.x * 256 + threadIdx.x;
  if (i >= total8) return;
  const int fin = flag[0];
  const size_t o = (size_t)i * 8;
  float x0, x1, x2, x3, x4, x5, x6, x7;
  ld4(src, o, fin, x0, x1, x2, x3);
  ld4(src, o + 4, fin, x4, x5, x6, x7);
  ushort4 lo, hi;
  lo.x = f2bf(x0); lo.y = f2bf(x1); lo.z = f2bf(x2); lo.w = f2bf(x3);
  hi.x = f2bf(x4); hi.y = f2bf(x5); hi.z = f2bf(x6); hi.w = f2bf(x7);
  *(ushort4*)(dst + o) = lo;
  *(ushort4*)(dst + o + 4) = hi;
}

// W [Kreal][Nreal] (row stride Nstride, element offset off) -> out bf16 [Np][Kp] = W^T zero-pad
__global__ void transpose_w(const int* __restrict__ flag, const void* __restrict__ W,
                            size_t off, int Kreal, int Nreal, int Nstride,
                            u16* __restrict__ out, int Kp, int Np) {
  const int idx = blockIdx.x * 256 + threadIdx.x;
  if (idx >= Np * Kp) return;
  const int n = idx / Kp, k = idx % Kp;
  float v = 0.f;
  if (k < Kreal && n < Nreal) v = ld1(W, off + (size_t)k * Nstride + n, flag[0]);
  out[idx] = f2bf(v);
}

// ---- MFMA GEMM: C[M, N] = act(A1@B1^T + A2@B2^T + bias) ----
// 128x128 tile, BK=32, 4 waves, 16x16x32 bf16. B^T bf16 [Npad][Kpad] pre-transposed.
// AM 0: A bf16, async global_load_lds staging. AM 1: A f32, manual staged (zero-pads K>=Kreal).
__device__ __forceinline__ void stage_bf16_async(const u16* __restrict__ G, size_t rbase,
                                                 int lda, int k0, u16* lds, int w, int lane) {
  #pragma unroll
  for (int t = 0; t < 2; ++t) {
    const int rr = (w << 5) + (t << 4) + (lane >> 2);
    const u16* gp = G + (rbase + rr) * (size_t)lda + k0 + ((lane & 3) << 3);
    __builtin_amdgcn_global_load_lds(
        (const __attribute__((address_space(1))) void*)gp,
        (__attribute__((address_space(3))) void*)(lds + (((w << 5) + (t << 4)) * 32)),
        16, 0, 0);
  }
}

__device__ __forceinline__ void stage_f32_manual(const float* __restrict__ G, int row0,
                                                 int lda, int k0, int Kreal,
                                                 u16* lds, int tid) {
  const int r = tid >> 1, half = tid & 1;
  const float* gp = G + (size_t)(row0 + r) * lda + k0 + (half << 4);
  #pragma unroll
  for (int qq = 0; qq < 4; ++qq) {
    const int kk = k0 + (half << 4) + (qq << 2);
    float4 v = make_float4(0.f, 0.f, 0.f, 0.f);
    if (kk < Kreal) v = *(const float4*)(gp + (qq << 2));
    ushort4 o;
    o.x = f2bf(v.x); o.y = f2bf(v.y); o.z = f2bf(v.z); o.w = f2bf(v.w);
    *(ushort4*)(lds + r * 32 + (half << 4) + (qq << 2)) = o;
  }
}

template <int AM>
__device__ __forceinline__ void kloop(const void* __restrict__ A, int lda, int Kreal, int Kpad,
                                      const u16* __restrict__ B, u16* As, u16* Bs,
                                      f32x4 (&acc)[4][4], int row0, int col0,
                                      int tid, int lane, int w, int wm, int wn, int ml, int q) {
  for (int k0 = 0; k0 < Kpad; k0 += 32) {
    if (AM == 0) stage_bf16_async((const u16*)A, (size_t)row0, lda, k0, As, w, lane);
    else         stage_f32_manual((const float*)A, row0, lda, k0, Kreal, As, tid);
    stage_bf16_async(B, (size_t)col0, Kpad, k0, Bs, w, lane);
    __syncthreads();
    short8 af[4], bfr[4];
    #pragma unroll
    for (int i = 0; i < 4; ++i)
      af[i] = *(const short8*)(As + ((wm << 6) + (i << 4) + ml) * 32 + (q << 3));
    #pragma unroll
    for (int j = 0; j < 4; ++j)
      bfr[j] = *(const short8*)(Bs + ((wn << 6) + (j << 4) + ml) * 32 + (q << 3));
    #pragma unroll
    for (int i = 0; i < 4; ++i)
      #pragma unroll
      for (int j = 0; j < 4; ++j)
        acc[i][j] = __builtin_amdgcn_mfma_f32_16x16x32_bf16(af[i], bfr[j], acc[i][j], 0, 0, 0);
    __syncthreads();
  }
}

template <int AM1, int AM2>
__global__ __launch_bounds__(256) void mfma_bt(
    const int* __restrict__ flag,
    const void* __restrict__ A1, int lda1, int K1real, int K1pad, const u16* __restrict__ B1,
    const void* __restrict__ A2, int lda2, int K2real, int K2pad, const u16* __restrict__ B2,
    const void* __restrict__ bias, int inBias,
    void* __restrict__ Cv, int ldc, int Nreal, int Npad, int relu, int cf32)
{
  __shared__ __attribute__((aligned(16))) u16 As[128 * 32];
  __shared__ __attribute__((aligned(16))) u16 Bs[128 * 32];
  const int tid = threadIdx.x;
  const int lane = tid & 63;
  const int w = tid >> 6;
  const int wm = w >> 1, wn = w & 1;
  const int row0 = blockIdx.y << 7;
  const int col0 = blockIdx.x << 7;
  const int ml = lane & 15, q = lane >> 4;

  f32x4 acc[4][4];
  #pragma unroll
  for (int i = 0; i < 4; ++i)
    #pragma unroll
    for (int j = 0; j < 4; ++j) {
      f32x4 z = {0.f, 0.f, 0.f, 0.f};
      acc[i][j] = z;
    }

  kloop<AM1>(A1, lda1, K1real, K1pad, B1, As, Bs, acc, row0, col0, tid, lane, w, wm, wn, ml, q);
  if constexpr (AM2 >= 0)
    kloop<AM2>(A2, lda2, K2real, K2pad, B2, As, Bs, acc, row0, col0, tid, lane, w, wm, wn, ml, q);

  const int fin = flag[0];
  // C/D layout (m89-verified): col = lane&15, row = (lane>>4)*4 + reg
  #pragma unroll
  for (int j = 0; j < 4; ++j) {
    const int col = col0 + (wn << 6) + (j << 4) + ml;
    if (col >= Npad) continue;
    float bv = 0.f;
    if (bias && col < Nreal) bv = ld1(bias, col, inBias ? fin : 0);
    #pragma unroll
    for (int i = 0; i < 4; ++i) {
      #pragma unroll
      for (int r = 0; r < 4; ++r) {
        const int row = row0 + (wm << 6) + (i << 4) + (q << 2) + r;
        float v = 0.f;
        if (col < Nreal) {
          v = acc[i][j][r] + bv;
          if (relu) v = fmaxf(v, 0.f);
        }
        if (cf32) ((float*)Cv)[(size_t)row * ldc + col] = v;
        else      ((u16*)Cv)[(size_t)row * ldc + col] = f2bf(v);
      }
    }
  }
}

// --- CSR build ---
__global__ void cnt_kernel(const int* __restrict__ edst, int* __restrict__ cnt) {
  const int i = blockIdx.x * 256 + threadIdx.x;
  if (i < EE) atomicAdd(&cnt[edst[i]], 1);
}

__global__ __launch_bounds__(1024) void scan_kernel(const int* __restrict__ cnt,
                                                    int* __restrict__ offs,
                                                    int* __restrict__ woffs) {
  __shared__ int part[1024];
  const int t = threadIdx.x;
  const int base = t * 16;
  int loc[16];
  int s = 0;
  #pragma unroll
  for (int i = 0; i < 16; ++i) { loc[i] = s; s += cnt[base + i]; }
  part[t] = s;
  __syncthreads();
  for (int off = 1; off < 1024; off <<= 1) {
    int v = (t >= off) ? part[t - off] : 0;
    __syncthreads();
    part[t] += v;
    __syncthreads();
  }
  const int chunk_excl = (t == 0) ? 0 : part[t - 1];
  #pragma unroll
  for (int i = 0; i < 16; ++i) {
    int o = chunk_excl + loc[i];
    offs[base + i] = o;
    woffs[base + i] = o;
  }
  if (t == 1023) offs[NN] = part[1023];
}

__global__ void scatter_kernel(const int* __restrict__ esrc, const int* __restrict__ edst,
                               int* __restrict__ woffs,
                               int* __restrict__ order, int* __restrict__ srcs) {
  const int e = blockIdx.x * 256 + threadIdx.x;
  if (e < EE) {
    const int d = edst[e];
    const int pos = atomicAdd(&woffs[d], 1);
    order[pos] = e;
    srcs[pos] = esrc[e];
  }
}

// appearance aggregation: one block per dst node; P12 interleaved [n][2048] (P1|P2).
// Edge loop unrolled x2 for ILP (8 independent FMA chains).
__global__ __launch_bounds__(256) void app_agg(
    const int* __restrict__ flag,
    const u16* __restrict__ P12, const void* __restrict__ s_f,
    const void* __restrict__ W_eb, const void* __restrict__ b_e,
    const int* __restrict__ offs, const int* __restrict__ order,
    const int* __restrict__ srcs, u16* __restrict__ aggn)
{
  const int fin = flag[0];
  const int n = blockIdx.x;
  const int tid = threadIdx.x;
  const int c4 = tid << 2;
  const void* W_es = eoff(W_eb, (size_t)2 * DF * DF, fin);

  float wx[16], wy[16], wz[16], ww[16];
  #pragma unroll
  for (int k = 0; k < 16; ++k)
    ld4(W_es, (size_t)k * DF + c4, fin, wx[k], wy[k], wz[k], ww[k]);

  float be0, be1, be2, be3;
  ld4(b_e, c4, fin, be0, be1, be2, be3);
  const ushort4 p2 = *(const ushort4*)(P12 + (size_t)n * 2048 + 1024 + c4);
  const float base0 = bf2f(p2.x) + be0;
  const float base1 = bf2f(p2.y) + be1;
  const float base2 = bf2f(p2.z) + be2;
  const float base3 = bf2f(p2.w) + be3;

  const int beg = offs[n], end = offs[n + 1];
  float a0 = 0.f, a1 = 0.f, a2 = 0.f, a3 = 0.f;
  int j = beg;
  for (; j + 2 <= end; j += 2) {
    const int eA = order[j],     eB = order[j + 1];
    const int sA = srcs[j],      sB = srcs[j + 1];
    float sfA[16], sfB[16];
    #pragma unroll
    for (int k = 0; k < 16; k += 4)
      ld4(s_f, (size_t)eA * DS + k, fin, sfA[k], sfA[k + 1], sfA[k + 2], sfA[k + 3]);
    #pragma unroll
    for (int k = 0; k < 16; k += 4)
      ld4(s_f, (size_t)eB * DS + k, fin, sfB[k], sfB[k + 1], sfB[k + 2], sfB[k + 3]);
    const ushort4 pA = *(const ushort4*)(P12 + (size_t)sA * 2048 + c4);
    const ushort4 pB = *(const ushort4*)(P12 + (size_t)sB * 2048 + c4);
    float uA0 = bf2f(pA.x) + base0, uB0 = bf2f(pB.x) + base0;
    float uA1 = bf2f(pA.y) + base1, uB1 = bf2f(pB.y) + base1;
    float uA2 = bf2f(pA.z) + base2, uB2 = bf2f(pB.z) + base2;
    float uA3 = bf2f(pA.w) + base3, uB3 = bf2f(pB.w) + base3;
    #pragma unroll
    for (int k = 0; k < 16; ++k) {
      uA0 = fmaf(sfA[k], wx[k], uA0); uB0 = fmaf(sfB[k], wx[k], uB0);
      uA1 = fmaf(sfA[k], wy[k], uA1); uB1 = fmaf(sfB[k], wy[k], uB1);
      uA2 = fmaf(sfA[k], wz[k], uA2); uB2 = fmaf(sfB[k], wz[k], uB2);
      uA3 = fmaf(sfA[k], ww[k], uA3); uB3 = fmaf(sfB[k], ww[k], uB3);
    }
    a0 += fmaxf(uA0, 0.f) + fmaxf(uB0, 0.f);
    a1 += fmaxf(uA1, 0.f) + fmaxf(uB1, 0.f);
    a2 += fmaxf(uA2, 0.f) + fmaxf(uB2, 0.f);
    a3 += fmaxf(uA3, 0.f) + fmaxf(uB3, 0.f);
  }
  if (j < end) {
    const int e = order[j], s = srcs[j];
    float sf[16];
    #pragma unroll
    for (int k = 0; k < 16; k += 4)
      ld4(s_f, (size_t)e * DS + k, fin, sf[k], sf[k + 1], sf[k + 2], sf[k + 3]);
    const ushort4 p1 = *(const ushort4*)(P12 + (size_t)s * 2048 + c4);
    float v0 = bf2f(p1.x) + base0;
    float v1 = bf2f(p1.y) + base1;
    float v2 = bf2f(p1.z) + base2;
    float v3 = bf2f(p1.w) + base3;
    #pragma unroll
    for (int k = 0; k < 16; ++k) {
      v0 = fmaf(sf[k], wx[k], v0);
      v1 = fmaf(sf[k], wy[k], v1);
      v2 = fmaf(sf[k], wz[k], v2);
      v3 = fmaf(sf[k], ww[k], v3);
    }
    a0 += fmaxf(v0, 0.f); a1 += fmaxf(v1, 0.f);
    a2 += fmaxf(v2, 0.f); a3 += fmaxf(v3, 0.f);
  }
  const float inv = 1.f / fmaxf((float)(end - beg), 1.f);
  ushort4 o;
  o.x = f2bf(a0 * inv); o.y = f2bf(a1 * inv);
  o.z = f2bf(a2 * inv); o.w = f2bf(a3 * inv);
  *(ushort4*)(aggn + (size_t)n * DF + c4) = o;
}

// language aggregation: Q12 interleaved [n][768] (Q1 @0 | Q2 @384); out [NN][DLP] zero-pad
__global__ __launch_bounds__(320) void lang_agg(
    const int* __restrict__ flag,
    const u16* __restrict__ Q12, const void* __restrict__ b_el,
    const int* __restrict__ offs, const int* __restrict__ srcs,
    u16* __restrict__ aggln)
{
  const int fin = flag[0];
  const int n = blockIdx.x;
  const int c = threadIdx.x;
  if (c >= DL) { aggln[(size_t)n * DLP + c] = 0; return; }
  const float base = bf2f(Q12[(size_t)n * 768 + 384 + c]) + ld1(b_el, c, fin);
  const int beg = offs[n], end = offs[n + 1];
  float a = 0.f;
  int j = beg;
  for (; j + 2 <= end; j += 2) {
    const float x0 = bf2f(Q12[(size_t)srcs[j] * 768 + c]);
    const float x1 = bf2f(Q12[(size_t)srcs[j + 1] * 768 + c]);
    a += fmaxf(x0 + base, 0.f) + fmaxf(x1 + base, 0.f);
  }
  if (j < end) a += fmaxf(bf2f(Q12[(size_t)srcs[j] * 768 + c]) + base, 0.f);
  aggln[(size_t)n * DLP + c] = f2bf(a / fmaxf((float)(end - beg), 1.f));
}

// pred[e] = RdRs[dst,0:117] + RdRs[src,128:245] + s_f_ro[e]@Wp_s + b_p
__global__ __launch_bounds__(128) void readout_kernel(
    const int* __restrict__ flag,
    const float* __restrict__ RdRs,
    const void* __restrict__ s_f_ro,
    const void* __restrict__ W_pb, size_t offWps,
    const void* __restrict__ b_p,
    const int* __restrict__ rsrc, const int* __restrict__ rdst, void* __restrict__ out)
{
  const int fin = flag[0];
  __shared__ float wps[16 * NC];
  const void* Wp_s = eoff(W_pb, offWps, fin);
  const int tid = threadIdx.x;
  for (int i = tid; i < 16 * NC; i += 128) wps[i] = ld1(Wp_s, i, fin);
  __syncthreads();
  const float bp = (tid < NC) ? ld1(b_p, tid, fin) : 0.f;

  const int e0 = blockIdx.x << 3;
  for (int ee = 0; ee < 8; ++ee) {
    const int e = e0 + ee;
    const int s = rsrc[e];
    const int d = rdst[e];
    if (tid < NC) {
      float acc = RdRs[(size_t)d * 256 + tid] + RdRs[(size_t)s * 256 + 128 + tid] + bp;
      #pragma unroll
      for (int k = 0; k < 16; ++k)
        acc = fmaf(ld1(s_f_ro, (size_t)e * DS + k, fin), wps[k * NC + tid], acc);
      if (fin) ((float*)out)[(size_t)e * NC + tid] = acc;
      else     ((u16*)out)[(size_t)e * NC + tid] = f2bf(acc);
    }
  }
}

extern "C" void kernel_launch(void* const* d_in, const int* in_sizes, int n_in,
                              void* d_out, int out_size, void* d_ws, size_t ws_size,
                              hipStream_t stream)
{
  const void* feat  = d_in[0];
  const void* w2v   = d_in[1];
  const void* s_f   = d_in[2];
  const void* s_fro = d_in[3];
  const void* W_e   = d_in[4];
  const void* b_e   = d_in[5];
  const void* W_el  = d_in[6];
  const void* b_el  = d_in[7];
  const void* W_nu  = d_in[8];
  const void* b_nu  = d_in[9];
  const void* W_nul = d_in[10];
  const void* b_nul = d_in[11];
  const void* W_p   = d_in[12];
  const void* b_p   = d_in[13];
  const int* esrc  = (const int*)d_in[14];
  const int* edst  = (const int*)d_in[15];
  const int* rsrc  = (const int*)d_in[16];
  const int* rdst  = (const int*)d_in[17];

  // ---- workspace layout: 172.8 MB total (proven envelope: 173.6 MB from R2) ----
  char* p = (char*)d_ws;
  int* flag  = (int*)p; p += 256;
  int* cnt   = (int*)p; p += (size_t)NN * 4;
  int* offs  = (int*)p; p += (size_t)(NN + 64) * 4;
  int* woffs = (int*)p; p += (size_t)NN * 4;
  int* order = (int*)p; p += (size_t)EE * 4;
  int* srcs  = (int*)p; p += (size_t)EE * 4;
  u16* featB  = (u16*)p; p += (size_t)NN * DF * 2;        // 32 MB bf16 feat
  u16* We12T  = (u16*)p; p += (size_t)2 * DF * DF * 2;    // [2048][1024]
  u16* Wnu1T  = (u16*)p; p += (size_t)DF * DF * 2;
  u16* Wnu2T  = (u16*)p; p += (size_t)DF * DF * 2;
  u16* Wel12T = (u16*)p; p += (size_t)2 * DLN * DLP * 2;  // [768][320]
  u16* Wnul1T = (u16*)p; p += (size_t)DLN * DLP * 2;
  u16* Wnul2T = (u16*)p; p += (size_t)DLN * DLP * 2;
  u16* WpFT2  = (u16*)p; p += (size_t)2 * NCP * DF * 2;   // [256][1024] (Rd-F | Rs-F)
  u16* WpLT2  = (u16*)p; p += (size_t)2 * NCP * DLP * 2;  // [256][320]  (Rd-L | Rs-L)
  u16* P12   = (u16*)p; p += (size_t)NN * 2048 * 2;       // 64 MB; later newf+newl
  u16* Q12   = (u16*)p; p += (size_t)NN * 768 * 2;        // 24 MB; later RdRs (16 MB f32)
  u16* aggln = (u16*)p; p += (size_t)NN * DLP * 2;        // 10 MB
  u16* aggn  = (u16*)p; p += (size_t)NN * DF * 2;         // 32 MB
  // aliases (stream-ordered: P12 dead after app_agg; Q12 dead after lang_agg)
  u16* newf = P12;
  u16* newl = P12 + (size_t)NN * DF;
  float* RdRs = (float*)Q12;

  detect_kernel<<<1, 64, 0, stream>>>((const unsigned int*)feat, flag);
  hipMemsetAsync(cnt, 0, (size_t)NN * 4, stream);
  cast_bf16<<<(NN * DF / 8 + 255) / 256, 256, 0, stream>>>(flag, feat, featB, NN * DF / 8);

  // ---- weight transposes (bf16, zero-padded) ----
  auto T = [&](const void* W, size_t off, int Kr, int Nr, int Nstr, u16* out, int Kp, int Np) {
    transpose_w<<<(Np * Kp + 255) / 256, 256, 0, stream>>>(flag, W, off, Kr, Nr, Nstr, out, Kp, Np);
  };
  T(W_e,   0,               DF, DF, DF, We12T,                      DF, DF);
  T(W_e,   (size_t)DF * DF, DF, DF, DF, We12T + (size_t)DF * DF,   DF, DF);
  T(W_nu,  0,               DF, DF, DF, Wnu1T, DF, DF);
  T(W_nu,  (size_t)DF * DF, DF, DF, DF, Wnu2T, DF, DF);
  T(W_el,  0,               DL, DL, DL, Wel12T,                      DLP, DLN);
  T(W_el,  (size_t)DL * DL, DL, DL, DL, Wel12T + (size_t)DLN * DLP,  DLP, DLN);
  T(W_nul, 0,               DL, DL, DL, Wnul1T, DLP, DLN);
  T(W_nul, (size_t)DL * DL, DL, DL, DL, Wnul2T, DLP, DLN);
  T(W_p,   0,                                DF, NC, NC, WpFT2,                      DF,  NCP);
  T(W_p,   (size_t)(DF + DL + DS + DL) * NC, DF, NC, NC, WpFT2 + (size_t)NCP * DF,   DF,  NCP);
  T(W_p,   (size_t)DF * NC,                  DL, NC, NC, WpLT2,                      DLP, NCP);
  T(W_p,   (size_t)(DF + DL + DS) * NC,      DL, NC, NC, WpLT2 + (size_t)NCP * DLP,  DLP, NCP);

  // ---- CSR build ----
  cnt_kernel<<<EE / 256, 256, 0, stream>>>(edst, cnt);
  scan_kernel<<<1, 1024, 0, stream>>>(cnt, offs, woffs);
  scatter_kernel<<<EE / 256, 256, 0, stream>>>(esrc, edst, woffs, order, srcs);

  const dim3 gP(2048 / 128, NN / 128);  // (16,128) fused P1|P2
  const dim3 gQ(768 / 128, NN / 128);   // (6,128)  fused Q1|Q2
  const dim3 gF(DF / 128, NN / 128);    // (8,128)
  const dim3 gL(DLN / 128, NN / 128);   // (3,128)
  const dim3 gR(256 / 128, NN / 128);   // (2,128)  fused Rd|Rs

  // projections
  mfma_bt<0, -1><<<gP, 256, 0, stream>>>(flag, featB, DF, DF, DF, We12T,
                                         nullptr, 0, 0, 0, nullptr,
                                         nullptr, 0, P12, 2048, 2048, 2048, 0, 0);
  mfma_bt<1, -1><<<gQ, 256, 0, stream>>>(flag, w2v, DL, DL, DLP, Wel12T,
                                         nullptr, 0, 0, 0, nullptr,
                                         nullptr, 0, Q12, 768, 768, 768, 0, 0);
  // aggregations (CSR, no atomics)
  lang_agg<<<NN, DLP, 0, stream>>>(flag, Q12, b_el, offs, srcs, aggln);
  app_agg<<<NN, 256, 0, stream>>>(flag, P12, s_f, W_e, b_e, offs, order, srcs, aggn);
  // node updates (newf/newl alias P12 - dead after app_agg)
  mfma_bt<1, 0><<<gL, 256, 0, stream>>>(flag, w2v, DL, DL, DLP, Wnul1T,
                                        aggln, DLP, DLP, DLP, Wnul2T,
                                        b_nul, 1, newl, DLP, DL, DLP, 1, 0);
  mfma_bt<0, 0><<<gF, 256, 0, stream>>>(flag, featB, DF, DF, DF, Wnu1T,
                                        aggn, DF, DF, DF, Wnu2T,
                                        b_nu, 1, newf, DF, DF, DF, 1, 0);
  // fused readout projections (f32, [NN][256]: cols 0-127 Rd, 128-255 Rs)
  mfma_bt<0, 0><<<gR, 256, 0, stream>>>(flag, newf, DF, DF, DF, WpFT2,
                                        newl, DLP, DLP, DLP, WpLT2,
                                        nullptr, 0, RdRs, 256, 256, 256, 0, 1);

  readout_kernel<<<ERO / 8, 128, 0, stream>>>(flag, RdRs, s_fro,
                                              W_p, (size_t)(DF + DL) * NC, b_p,
                                              rsrc, rdst, d_out);
}

// Round 6
// 656.321 us; speedup vs baseline: 7.0392x; 1.2086x over previous
//
#include <hip/hip_runtime.h>

typedef unsigned short u16;
typedef __attribute__((ext_vector_type(8))) short short8;
typedef __attribute__((ext_vector_type(4))) float f32x4;

#define NN 16384   // nodes
#define EE 131072  // edges
#define ERO 32768  // readout edges
#define DF 1024    // appearance dim
#define DL 300     // word2vec dim
#define DLP 320    // K-padded language dim (mult of 32)
#define DLN 384    // N-padded language B^T storage rows (3 tiles of 128)
#define DS 16      // spatial dim
#define NC 117     // classes
#define NCP 128    // padded classes

__device__ __forceinline__ float bf2f(u16 x) {
  unsigned int u = ((unsigned int)x) << 16;
  float f;
  __builtin_memcpy(&f, &u, 4);
  return f;
}
__device__ __forceinline__ u16 f2bf(float f) {
  unsigned int u;
  __builtin_memcpy(&u, &f, 4);
  u = (u + 0x7FFFu + ((u >> 16) & 1u)) >> 16;
  return (u16)u;
}
__device__ __forceinline__ float ld1(const void* p, size_t i, int f) {
  return f ? ((const float*)p)[i] : bf2f(((const u16*)p)[i]);
}
__device__ __forceinline__ void ld4(const void* p, size_t i, int f,
                                    float& x, float& y, float& z, float& w) {
  if (f) {
    float4 v = *(const float4*)((const float*)p + i);
    x = v.x; y = v.y; z = v.z; w = v.w;
  } else {
    ushort4 v = *(const ushort4*)((const u16*)p + i);
    x = bf2f(v.x); y = bf2f(v.y); z = bf2f(v.z); w = bf2f(v.w);
  }
}
__device__ __forceinline__ const void* eoff(const void* p, size_t off, int f) {
  return f ? (const void*)((const float*)p + off) : (const void*)((const u16*)p + off);
}

// dtype probe (measured: f32 on this harness; kept adaptive for safety)
__global__ void detect_kernel(const unsigned int* __restrict__ w, int* __restrict__ flag) {
  unsigned int x = w[threadIdx.x];
  int e = (x >> 7) & 0xFF;
  int ok = (e >= 97 && e <= 157);
  unsigned long long m = __ballot(ok);
  if (threadIdx.x == 0) flag[0] = (__popcll(m) >= 48) ? 0 : 1;  // 0=bf16, 1=f32
}

// contiguous cast to bf16, 8 elems/thread
__global__ void cast_bf16(const int* __restrict__ flag, const void* __restrict__ src,
                          u16* __restrict__ dst, int total8) {
  const int i = blockIdx.x * 256 + threadIdx.x;
  if (i >= total8) return;
  const int fin = flag[0];
  const size_t o = (size_t)i * 8;
  float x0, x1, x2, x3, x4, x5, x6, x7;
  ld4(src, o, fin, x0, x1, x2, x3);
  ld4(src, o + 4, fin, x4, x5, x6, x7);
  ushort4 lo, hi;
  lo.x = f2bf(x0); lo.y = f2bf(x1); lo.z = f2bf(x2); lo.w = f2bf(x3);
  hi.x = f2bf(x4); hi.y = f2bf(x5); hi.z = f2bf(x6); hi.w = f2bf(x7);
  *(ushort4*)(dst + o) = lo;
  *(ushort4*)(dst + o + 4) = hi;
}

// ---- fused weight prep: 12 transposes in one launch ----
struct TJob {
  const void* W; long off;
  int Kr, Nr, Nstr, Kp, Np, blk0;
};
struct TPack { TJob j[12]; int nj; };

__global__ void prep_weights(const int* __restrict__ flag, TPack P, u16* __restrict__ outbase,
                             const long* __restrict__ outoffs_unused) {
  // out pointer packed in W? no: out = outbase + per-job offset stored in blk0's sibling.
}

// simpler: carry out-ptr inside the job
struct TJob2 {
  const void* W; long off;
  u16* out;
  int Kr, Nr, Nstr, Kp, Np, blk0;
};
struct TPack2 { TJob2 j[12]; int nj; };

__global__ void prep_weights2(const int* __restrict__ flag, TPack2 P) {
  int b = blockIdx.x;
  int ji = 0;
  while (ji + 1 < P.nj && b >= P.j[ji + 1].blk0) ++ji;
  const TJob2 J = P.j[ji];
  const int idx = (b - J.blk0) * 256 + threadIdx.x;
  if (idx >= J.Np * J.Kp) return;
  const int n = idx / J.Kp, k = idx % J.Kp;
  float v = 0.f;
  if (k < J.Kr && n < J.Nr) v = ld1(J.W, (size_t)J.off + (size_t)k * J.Nstr + n, flag[0]);
  J.out[idx] = f2bf(v);
}

// ---- batched MFMA GEMM: C = act(A1@B1^T [+ A2@B2^T] + bias) ----
// 128x128 tile, BK=32, 4 waves, 16x16x32 bf16. B^T bf16 [Npad][Kpad] pre-transposed.
// am 0: A bf16 (async global_load_lds); 1: A f32 (manual stage, zero-pad K>=Kreal).
__device__ __forceinline__ void stage_bf16_async(const u16* __restrict__ G, size_t rbase,
                                                 int lda, int k0, u16* lds, int w, int lane) {
  #pragma unroll
  for (int t = 0; t < 2; ++t) {
    const int rr = (w << 5) + (t << 4) + (lane >> 2);
    const u16* gp = G + (rbase + rr) * (size_t)lda + k0 + ((lane & 3) << 3);
    __builtin_amdgcn_global_load_lds(
        (const __attribute__((address_space(1))) void*)gp,
        (__attribute__((address_space(3))) void*)(lds + (((w << 5) + (t << 4)) * 32)),
        16, 0, 0);
  }
}

__device__ __forceinline__ void stage_f32_manual(const float* __restrict__ G, int row0,
                                                 int lda, int k0, int Kreal,
                                                 u16* lds, int tid) {
  const int r = tid >> 1, half = tid & 1;
  const float* gp = G + (size_t)(row0 + r) * lda + k0 + (half << 4);
  #pragma unroll
  for (int qq = 0; qq < 4; ++qq) {
    const int kk = k0 + (half << 4) + (qq << 2);
    float4 v = make_float4(0.f, 0.f, 0.f, 0.f);
    if (kk < Kreal) v = *(const float4*)(gp + (qq << 2));
    ushort4 o;
    o.x = f2bf(v.x); o.y = f2bf(v.y); o.z = f2bf(v.z); o.w = f2bf(v.w);
    *(ushort4*)(lds + r * 32 + (half << 4) + (qq << 2)) = o;
  }
}

__device__ __forceinline__ void kloop(int am, const void* __restrict__ A, int lda,
                                      int Kreal, int Kpad, const u16* __restrict__ B,
                                      u16* As, u16* Bs, f32x4 (&acc)[4][4],
                                      int row0, int col0,
                                      int tid, int lane, int w, int wm, int wn, int ml, int q) {
  for (int k0 = 0; k0 < Kpad; k0 += 32) {
    if (am == 0) stage_bf16_async((const u16*)A, (size_t)row0, lda, k0, As, w, lane);
    else         stage_f32_manual((const float*)A, row0, lda, k0, Kreal, As, tid);
    stage_bf16_async(B, (size_t)col0, Kpad, k0, Bs, w, lane);
    __syncthreads();
    short8 af[4], bfr[4];
    #pragma unroll
    for (int i = 0; i < 4; ++i)
      af[i] = *(const short8*)(As + ((wm << 6) + (i << 4) + ml) * 32 + (q << 3));
    #pragma unroll
    for (int j = 0; j < 4; ++j)
      bfr[j] = *(const short8*)(Bs + ((wn << 6) + (j << 4) + ml) * 32 + (q << 3));
    #pragma unroll
    for (int i = 0; i < 4; ++i)
      #pragma unroll
      for (int j = 0; j < 4; ++j)
        acc[i][j] = __builtin_amdgcn_mfma_f32_16x16x32_bf16(af[i], bfr[j], acc[i][j], 0, 0, 0);
    __syncthreads();
  }
}

struct GJob {
  const void* A1; const u16* B1;
  const void* A2; const u16* B2;
  const void* bias; void* C;
  int lda1, K1real, K1pad, am1;
  int lda2, K2real, K2pad, am2;   // am2 = -1 -> no second pair
  int inBias, ldc, Nreal, Npad, relu, cf32;
  int gx, gy, blk0;               // tile grid; gy % 8 == 0
};
struct GPack { GJob j[2]; int nj; };

__global__ __launch_bounds__(256) void mfma_jobs(const int* __restrict__ flag, GPack P) {
  const int b = blockIdx.x;
  int ji = 0;
  if (P.nj > 1 && b >= P.j[1].blk0) ji = 1;
  const GJob J = P.j[ji];
  const int t = b - J.blk0;
  // XCD-aware swizzle: each XCD owns a row band, sweeps columns within a row tile
  const int xcd = t & 7, s = t >> 3;
  const int row_t = xcd * (J.gy >> 3) + s / J.gx;
  const int col_t = s % J.gx;
  const int row0 = row_t << 7;
  const int col0 = col_t << 7;

  __shared__ __attribute__((aligned(16))) u16 As[128 * 32];
  __shared__ __attribute__((aligned(16))) u16 Bs[128 * 32];
  const int tid = threadIdx.x;
  const int lane = tid & 63;
  const int w = tid >> 6;
  const int wm = w >> 1, wn = w & 1;
  const int ml = lane & 15, q = lane >> 4;

  f32x4 acc[4][4];
  #pragma unroll
  for (int i = 0; i < 4; ++i)
    #pragma unroll
    for (int j = 0; j < 4; ++j) {
      f32x4 z = {0.f, 0.f, 0.f, 0.f};
      acc[i][j] = z;
    }

  kloop(J.am1, J.A1, J.lda1, J.K1real, J.K1pad, J.B1, As, Bs, acc,
        row0, col0, tid, lane, w, wm, wn, ml, q);
  if (J.am2 >= 0)
    kloop(J.am2, J.A2, J.lda2, J.K2real, J.K2pad, J.B2, As, Bs, acc,
          row0, col0, tid, lane, w, wm, wn, ml, q);

  const int fin = flag[0];
  // C/D layout (m89-verified): col = lane&15, row = (lane>>4)*4 + reg
  #pragma unroll
  for (int j = 0; j < 4; ++j) {
    const int col = col0 + (wn << 6) + (j << 4) + ml;
    if (col >= J.Npad) continue;
    float bv = 0.f;
    if (J.bias && col < J.Nreal) bv = ld1(J.bias, col, J.inBias ? fin : 0);
    #pragma unroll
    for (int i = 0; i < 4; ++i) {
      #pragma unroll
      for (int r = 0; r < 4; ++r) {
        const int row = row0 + (wm << 6) + (i << 4) + (q << 2) + r;
        float v = 0.f;
        if (col < J.Nreal) {
          v = acc[i][j][r] + bv;
          if (J.relu) v = fmaxf(v, 0.f);
        }
        if (J.cf32) ((float*)J.C)[(size_t)row * J.ldc + col] = v;
        else        ((u16*)J.C)[(size_t)row * J.ldc + col] = f2bf(v);
      }
    }
  }
}

// --- CSR build ---
__global__ void cnt_kernel(const int* __restrict__ edst, int* __restrict__ cnt) {
  const int i = blockIdx.x * 256 + threadIdx.x;
  if (i < EE) atomicAdd(&cnt[edst[i]], 1);
}

__global__ __launch_bounds__(1024) void scan_kernel(const int* __restrict__ cnt,
                                                    int* __restrict__ offs,
                                                    int* __restrict__ woffs) {
  __shared__ int part[1024];
  const int t = threadIdx.x;
  const int base = t * 16;
  int loc[16];
  int s = 0;
  #pragma unroll
  for (int i = 0; i < 16; ++i) { loc[i] = s; s += cnt[base + i]; }
  part[t] = s;
  __syncthreads();
  for (int off = 1; off < 1024; off <<= 1) {
    int v = (t >= off) ? part[t - off] : 0;
    __syncthreads();
    part[t] += v;
    __syncthreads();
  }
  const int chunk_excl = (t == 0) ? 0 : part[t - 1];
  #pragma unroll
  for (int i = 0; i < 16; ++i) {
    int o = chunk_excl + loc[i];
    offs[base + i] = o;
    woffs[base + i] = o;
  }
  if (t == 1023) offs[NN] = part[1023];
}

__global__ void scatter_kernel(const int* __restrict__ esrc, const int* __restrict__ edst,
                               int* __restrict__ woffs,
                               int* __restrict__ order, int* __restrict__ srcs) {
  const int e = blockIdx.x * 256 + threadIdx.x;
  if (e < EE) {
    const int d = edst[e];
    const int pos = atomicAdd(&woffs[d], 1);
    order[pos] = e;
    srcs[pos] = esrc[e];
  }
}

// appearance aggregation: one block per dst node; P12 interleaved [n][2048] (P1|P2).
// Edge loop unrolled x4 (16 independent FMA chains) — latency-bound per R4/R5 counters.
__global__ __launch_bounds__(256) void app_agg(
    const int* __restrict__ flag,
    const u16* __restrict__ P12, const void* __restrict__ s_f,
    const void* __restrict__ W_eb, const void* __restrict__ b_e,
    const int* __restrict__ offs, const int* __restrict__ order,
    const int* __restrict__ srcs, u16* __restrict__ aggn)
{
  const int fin = flag[0];
  const int n = blockIdx.x;
  const int tid = threadIdx.x;
  const int c4 = tid << 2;
  const void* W_es = eoff(W_eb, (size_t)2 * DF * DF, fin);

  float wx[16], wy[16], wz[16], ww[16];
  #pragma unroll
  for (int k = 0; k < 16; ++k)
    ld4(W_es, (size_t)k * DF + c4, fin, wx[k], wy[k], wz[k], ww[k]);

  float be0, be1, be2, be3;
  ld4(b_e, c4, fin, be0, be1, be2, be3);
  const ushort4 p2 = *(const ushort4*)(P12 + (size_t)n * 2048 + 1024 + c4);
  const float base0 = bf2f(p2.x) + be0;
  const float base1 = bf2f(p2.y) + be1;
  const float base2 = bf2f(p2.z) + be2;
  const float base3 = bf2f(p2.w) + be3;

  const int beg = offs[n], end = offs[n + 1];
  float a0 = 0.f, a1 = 0.f, a2 = 0.f, a3 = 0.f;
  int j = beg;
  for (; j + 4 <= end; j += 4) {
    int ee[4], ss[4];
    #pragma unroll
    for (int m = 0; m < 4; ++m) { ee[m] = order[j + m]; ss[m] = srcs[j + m]; }
    float u0[4], u1[4], u2[4], u3[4], sfv[4][16];
    #pragma unroll
    for (int m = 0; m < 4; ++m) {
      #pragma unroll
      for (int k = 0; k < 16; k += 4)
        ld4(s_f, (size_t)ee[m] * DS + k, fin,
            sfv[m][k], sfv[m][k + 1], sfv[m][k + 2], sfv[m][k + 3]);
      const ushort4 pm = *(const ushort4*)(P12 + (size_t)ss[m] * 2048 + c4);
      u0[m] = bf2f(pm.x) + base0;
      u1[m] = bf2f(pm.y) + base1;
      u2[m] = bf2f(pm.z) + base2;
      u3[m] = bf2f(pm.w) + base3;
    }
    #pragma unroll
    for (int k = 0; k < 16; ++k)
      #pragma unroll
      for (int m = 0; m < 4; ++m) {
        u0[m] = fmaf(sfv[m][k], wx[k], u0[m]);
        u1[m] = fmaf(sfv[m][k], wy[k], u1[m]);
        u2[m] = fmaf(sfv[m][k], wz[k], u2[m]);
        u3[m] = fmaf(sfv[m][k], ww[k], u3[m]);
      }
    #pragma unroll
    for (int m = 0; m < 4; ++m) {
      a0 += fmaxf(u0[m], 0.f); a1 += fmaxf(u1[m], 0.f);
      a2 += fmaxf(u2[m], 0.f); a3 += fmaxf(u3[m], 0.f);
    }
  }
  for (; j < end; ++j) {
    const int e = order[j], s = srcs[j];
    float sf[16];
    #pragma unroll
    for (int k = 0; k < 16; k += 4)
      ld4(s_f, (size_t)e * DS + k, fin, sf[k], sf[k + 1], sf[k + 2], sf[k + 3]);
    const ushort4 p1 = *(const ushort4*)(P12 + (size_t)s * 2048 + c4);
    float v0 = bf2f(p1.x) + base0;
    float v1 = bf2f(p1.y) + base1;
    float v2 = bf2f(p1.z) + base2;
    float v3 = bf2f(p1.w) + base3;
    #pragma unroll
    for (int k = 0; k < 16; ++k) {
      v0 = fmaf(sf[k], wx[k], v0);
      v1 = fmaf(sf[k], wy[k], v1);
      v2 = fmaf(sf[k], wz[k], v2);
      v3 = fmaf(sf[k], ww[k], v3);
    }
    a0 += fmaxf(v0, 0.f); a1 += fmaxf(v1, 0.f);
    a2 += fmaxf(v2, 0.f); a3 += fmaxf(v3, 0.f);
  }
  const float inv = 1.f / fmaxf((float)(end - beg), 1.f);
  ushort4 o;
  o.x = f2bf(a0 * inv); o.y = f2bf(a1 * inv);
  o.z = f2bf(a2 * inv); o.w = f2bf(a3 * inv);
  *(ushort4*)(aggn + (size_t)n * DF + c4) = o;
}

// language aggregation: Q12 interleaved [n][768] (Q1 @0 | Q2 @384); out [NN][DLP] zero-pad
__global__ __launch_bounds__(320) void lang_agg(
    const int* __restrict__ flag,
    const u16* __restrict__ Q12, const void* __restrict__ b_el,
    const int* __restrict__ offs, const int* __restrict__ srcs,
    u16* __restrict__ aggln)
{
  const int fin = flag[0];
  const int n = blockIdx.x;
  const int c = threadIdx.x;
  if (c >= DL) { aggln[(size_t)n * DLP + c] = 0; return; }
  const float base = bf2f(Q12[(size_t)n * 768 + 384 + c]) + ld1(b_el, c, fin);
  const int beg = offs[n], end = offs[n + 1];
  float s0 = 0.f, s1 = 0.f, s2 = 0.f, s3 = 0.f;
  int j = beg;
  for (; j + 4 <= end; j += 4) {
    s0 += fmaxf(bf2f(Q12[(size_t)srcs[j] * 768 + c]) + base, 0.f);
    s1 += fmaxf(bf2f(Q12[(size_t)srcs[j + 1] * 768 + c]) + base, 0.f);
    s2 += fmaxf(bf2f(Q12[(size_t)srcs[j + 2] * 768 + c]) + base, 0.f);
    s3 += fmaxf(bf2f(Q12[(size_t)srcs[j + 3] * 768 + c]) + base, 0.f);
  }
  for (; j < end; ++j) s0 += fmaxf(bf2f(Q12[(size_t)srcs[j] * 768 + c]) + base, 0.f);
  const float a = (s0 + s1) + (s2 + s3);
  aggln[(size_t)n * DLP + c] = f2bf(a / fmaxf((float)(end - beg), 1.f));
}

// pred[e] = RdRs[dst,0:117] + RdRs[src,128:245] + s_f_ro[e]@Wp_s + b_p
// 256 threads process 2 edges concurrently (tid>>7 = edge slot), 8 edges per block.
__global__ __launch_bounds__(256) void readout_kernel(
    const int* __restrict__ flag,
    const float* __restrict__ RdRs,
    const void* __restrict__ s_f_ro,
    const void* __restrict__ W_pb, size_t offWps,
    const void* __restrict__ b_p,
    const int* __restrict__ rsrc, const int* __restrict__ rdst, void* __restrict__ out)
{
  const int fin = flag[0];
  __shared__ float wps[16 * NC];
  const void* Wp_s = eoff(W_pb, offWps, fin);
  const int tid = threadIdx.x;
  for (int i = tid; i < 16 * NC; i += 256) wps[i] = ld1(Wp_s, i, fin);
  __syncthreads();
  const int slot = tid >> 7;        // 0 or 1
  const int c = tid & 127;
  const float bp = (c < NC) ? ld1(b_p, c, fin) : 0.f;

  const int e0 = (blockIdx.x << 3) + slot;
  #pragma unroll
  for (int ee = 0; ee < 8; ee += 2) {
    const int e = e0 + ee;
    const int s = rsrc[e];
    const int d = rdst[e];
    if (c < NC) {
      float acc = RdRs[(size_t)d * 256 + c] + RdRs[(size_t)s * 256 + 128 + c] + bp;
      #pragma unroll
      for (int k = 0; k < 16; ++k)
        acc = fmaf(ld1(s_f_ro, (size_t)e * DS + k, fin), wps[k * NC + c], acc);
      if (fin) ((float*)out)[(size_t)e * NC + c] = acc;
      else     ((u16*)out)[(size_t)e * NC + c] = f2bf(acc);
    }
  }
}

extern "C" void kernel_launch(void* const* d_in, const int* in_sizes, int n_in,
                              void* d_out, int out_size, void* d_ws, size_t ws_size,
                              hipStream_t stream)
{
  const void* feat  = d_in[0];
  const void* w2v   = d_in[1];
  const void* s_f   = d_in[2];
  const void* s_fro = d_in[3];
  const void* W_e   = d_in[4];
  const void* b_e   = d_in[5];
  const void* W_el  = d_in[6];
  const void* b_el  = d_in[7];
  const void* W_nu  = d_in[8];
  const void* b_nu  = d_in[9];
  const void* W_nul = d_in[10];
  const void* b_nul = d_in[11];
  const void* W_p   = d_in[12];
  const void* b_p   = d_in[13];
  const int* esrc  = (const int*)d_in[14];
  const int* edst  = (const int*)d_in[15];
  const int* rsrc  = (const int*)d_in[16];
  const int* rdst  = (const int*)d_in[17];

  // ---- workspace layout: ~172.8 MB (R4-proven envelope) ----
  char* p = (char*)d_ws;
  int* flag  = (int*)p; p += 256;
  int* cnt   = (int*)p; p += (size_t)NN * 4;
  int* offs  = (int*)p; p += (size_t)(NN + 64) * 4;
  int* woffs = (int*)p; p += (size_t)NN * 4;
  int* order = (int*)p; p += (size_t)EE * 4;
  int* srcs  = (int*)p; p += (size_t)EE * 4;
  u16* featB  = (u16*)p; p += (size_t)NN * DF * 2;        // 32 MB bf16 feat
  u16* We12T  = (u16*)p; p += (size_t)2 * DF * DF * 2;    // [2048][1024]
  u16* Wnu1T  = (u16*)p; p += (size_t)DF * DF * 2;
  u16* Wnu2T  = (u16*)p; p += (size_t)DF * DF * 2;
  u16* Wel12T = (u16*)p; p += (size_t)2 * DLN * DLP * 2;  // [768][320]
  u16* Wnul1T = (u16*)p; p += (size_t)DLN * DLP * 2;
  u16* Wnul2T = (u16*)p; p += (size_t)DLN * DLP * 2;
  u16* WpFT2  = (u16*)p; p += (size_t)2 * NCP * DF * 2;   // [256][1024] (Rd-F | Rs-F)
  u16* WpLT2  = (u16*)p; p += (size_t)2 * NCP * DLP * 2;  // [256][320]  (Rd-L | Rs-L)
  u16* P12   = (u16*)p; p += (size_t)NN * 2048 * 2;       // 64 MB; later newf+newl
  u16* Q12   = (u16*)p; p += (size_t)NN * 768 * 2;        // 24 MB; later RdRs (16 MB f32)
  u16* aggln = (u16*)p; p += (size_t)NN * DLP * 2;        // 10 MB
  u16* aggn  = (u16*)p; p += (size_t)NN * DF * 2;         // 32 MB
  // aliases (stream-ordered: P12 dead after app_agg; Q12 dead after lang_agg)
  u16* newf = P12;
  u16* newl = P12 + (size_t)NN * DF;
  float* RdRs = (float*)Q12;

  detect_kernel<<<1, 64, 0, stream>>>((const unsigned int*)feat, flag);
  hipMemsetAsync(cnt, 0, (size_t)NN * 4, stream);
  cast_bf16<<<(NN * DF / 8 + 255) / 256, 256, 0, stream>>>(flag, feat, featB, NN * DF / 8);

  // ---- fused weight prep (12 transposes, one launch) ----
  TPack2 tp{};
  int tb = 0, tn = 0;
  auto T = [&](const void* W, long off, int Kr, int Nr, int Nstr, u16* out, int Kp, int Np) {
    tp.j[tn] = TJob2{W, off, out, Kr, Nr, Nstr, Kp, Np, tb};
    tb += (Np * Kp + 255) / 256;
    ++tn;
  };
  T(W_e,   0,                   DF, DF, DF, We12T,                     DF, DF);
  T(W_e,   (long)DF * DF,       DF, DF, DF, We12T + (size_t)DF * DF,   DF, DF);
  T(W_nu,  0,                   DF, DF, DF, Wnu1T, DF, DF);
  T(W_nu,  (long)DF * DF,       DF, DF, DF, Wnu2T, DF, DF);
  T(W_el,  0,                   DL, DL, DL, Wel12T,                     DLP, DLN);
  T(W_el,  (long)DL * DL,       DL, DL, DL, Wel12T + (size_t)DLN * DLP, DLP, DLN);
  T(W_nul, 0,                   DL, DL, DL, Wnul1T, DLP, DLN);
  T(W_nul, (long)DL * DL,       DL, DL, DL, Wnul2T, DLP, DLN);
  T(W_p,   0,                                DF, NC, NC, WpFT2,                     DF,  NCP);
  T(W_p,   (long)(DF + DL + DS + DL) * NC,   DF, NC, NC, WpFT2 + (size_t)NCP * DF,  DF,  NCP);
  T(W_p,   (long)DF * NC,                    DL, NC, NC, WpLT2,                     DLP, NCP);
  T(W_p,   (long)(DF + DL + DS) * NC,        DL, NC, NC, WpLT2 + (size_t)NCP * DLP, DLP, NCP);
  tp.nj = tn;
  prep_weights2<<<tb, 256, 0, stream>>>(flag, tp);

  // ---- CSR build ----
  cnt_kernel<<<EE / 256, 256, 0, stream>>>(edst, cnt);
  scan_kernel<<<1, 1024, 0, stream>>>(cnt, offs, woffs);
  scatter_kernel<<<EE / 256, 256, 0, stream>>>(esrc, edst, woffs, order, srcs);

  // ---- GEMM phase 1: P12 (featB @ We12T^T) + Q12 (w2v @ Wel12T^T) ----
  {
    GPack g{};
    g.j[0] = GJob{featB, We12T, nullptr, nullptr, nullptr, P12,
                  DF, DF, DF, 0,    0, 0, 0, -1,
                  0, 2048, 2048, 2048, 0, 0,  16, 128, 0};
    g.j[1] = GJob{w2v, Wel12T, nullptr, nullptr, nullptr, Q12,
                  DL, DL, DLP, 1,   0, 0, 0, -1,
                  0, 768, 768, 768, 0, 0,    6, 128, 2048};
    g.nj = 2;
    mfma_jobs<<<2048 + 768, 256, 0, stream>>>(flag, g);
  }

  // ---- aggregations (CSR, no atomics) ----
  lang_agg<<<NN, DLP, 0, stream>>>(flag, Q12, b_el, offs, srcs, aggln);
  app_agg<<<NN, 256, 0, stream>>>(flag, P12, s_f, W_e, b_e, offs, order, srcs, aggn);

  // ---- GEMM phase 2: node updates (newf/newl alias P12 - dead after app_agg) ----
  {
    GPack g{};
    g.j[0] = GJob{featB, Wnu1T, aggn, Wnu2T, b_nu, newf,
                  DF, DF, DF, 0,    DF, DF, DF, 0,
                  1, DF, DF, DF, 1, 0,       8, 128, 0};
    g.j[1] = GJob{w2v, Wnul1T, aggln, Wnul2T, b_nul, newl,
                  DL, DL, DLP, 1,   DLP, DLP, DLP, 0,
                  1, DLP, DL, DLP, 1, 0,     3, 128, 1024};
    g.nj = 2;
    mfma_jobs<<<1024 + 384, 256, 0, stream>>>(flag, g);
  }

  // ---- GEMM phase 3: fused readout projections (f32, [NN][256]: Rd | Rs) ----
  {
    GPack g{};
    g.j[0] = GJob{newf, WpFT2, newl, WpLT2, nullptr, RdRs,
                  DF, DF, DF, 0,    DLP, DLP, DLP, 0,
                  0, 256, 256, 256, 0, 1,    2, 128, 0};
    g.nj = 1;
    mfma_jobs<<<256, 256, 0, stream>>>(flag, g);
  }

  readout_kernel<<<ERO / 8, 256, 0, stream>>>(flag, RdRs, s_fro,
                                              W_p, (size_t)(DF + DL) * NC, b_p,
                                              rsrc, rdst, d_out);
}